// Round 1
// baseline (1210.182 us; speedup 1.0000x reference)
//
#include <hip/hip_runtime.h>
#include <cmath>

constexpr int N_NODES = 10000;
constexpr int D_IN = 128;   // GraphConv dim
constexpr int H_DIM = 256;  // MLP hidden

// ---------------------------------------------------------------------------
// Scatter-add aggregation: agg[dst[e]][:] += x[src[e]][:]
// One thread per (edge, 4-float chunk): 32 threads/edge, float4 gather,
// 4 HW float atomics (global_atomic_add_f32 via unsafeAtomicAdd).
// ---------------------------------------------------------------------------
__global__ __launch_bounds__(256)
void scatter_add_kernel(const float* __restrict__ x,
                        const int* __restrict__ ei,
                        float* __restrict__ agg, int E) {
    int gid = blockIdx.x * blockDim.x + threadIdx.x;
    int e = gid >> 5;
    if (e >= E) return;
    int c = (gid & 31) * 4;
    int s = ei[e];        // src row
    int d = ei[E + e];    // dst row
    const float4 v = *reinterpret_cast<const float4*>(x + (size_t)s * D_IN + c);
    float* a = agg + (size_t)d * D_IN + c;
    unsafeAtomicAdd(a + 0, v.x);
    unsafeAtomicAdd(a + 1, v.y);
    unsafeAtomicAdd(a + 2, v.z);
    unsafeAtomicAdd(a + 3, v.w);
}

// ---------------------------------------------------------------------------
// C[M,N] = act( A@W^T + bias ), A row-major [M,K], W row-major [N,K].
// Concat-K support for the GraphConv layer: A = [A1(K1) | A2(K2)],
// W = [Wa(K1) | Wb(K2)]  (K1, K2 multiples of BK; chunk source is uniform).
// Tiles: BM=BN=64, BK=16, 256 threads, 4x4 microtile.
// LDS transposed layout [BK][BM+4] so microtile reads are ds_read_b128;
// +4 pad keeps 16B alignment and spreads banks.
// ---------------------------------------------------------------------------
template <int ACT>  // 0 = none, 1 = relu
__global__ __launch_bounds__(256)
void gemm_bias_act(const float* __restrict__ A1, const float* __restrict__ A2,
                   const float* __restrict__ Wa, const float* __restrict__ Wb,
                   const float* __restrict__ bias, float* __restrict__ C,
                   int M, int N, int K1, int K2) {
    constexpr int BM = 64, BN = 64, BK = 16;
    __shared__ float As[BK][BM + 4];
    __shared__ float Ws[BK][BN + 4];
    const int t = threadIdx.x;
    const int m0 = blockIdx.y * BM;
    const int n0 = blockIdx.x * BN;
    const int tx = t & 15;      // col group: cols n0 + tx*4 ..
    const int ty = t >> 4;      // row group: rows m0 + ty*4 ..
    const int lr = t >> 2;      // 0..63: tile row (A) / tile col (W) to load
    const int lk = (t & 3) * 4; // k sub-offset 0/4/8/12
    float acc[4][4] = {};
    const int Ktot = K1 + K2;
    for (int k0 = 0; k0 < Ktot; k0 += BK) {
        const float* Ap; const float* Wp; int kbase, ld;
        if (k0 < K1) { Ap = A1; Wp = Wa; kbase = k0;      ld = K1; }
        else         { Ap = A2; Wp = Wb; kbase = k0 - K1; ld = K2; }
        int row = m0 + lr;
        int rclamp = row < M ? row : M - 1;  // stores are guarded later
        float4 av = *reinterpret_cast<const float4*>(Ap + (size_t)rclamp * ld + kbase + lk);
        float4 wv = *reinterpret_cast<const float4*>(Wp + (size_t)(n0 + lr) * ld + kbase + lk);
        __syncthreads();  // protect LDS from previous iteration's readers
        As[lk + 0][lr] = av.x; As[lk + 1][lr] = av.y;
        As[lk + 2][lr] = av.z; As[lk + 3][lr] = av.w;
        Ws[lk + 0][lr] = wv.x; Ws[lk + 1][lr] = wv.y;
        Ws[lk + 2][lr] = wv.z; Ws[lk + 3][lr] = wv.w;
        __syncthreads();
#pragma unroll
        for (int kk = 0; kk < BK; ++kk) {
            float4 a4 = *reinterpret_cast<const float4*>(&As[kk][ty * 4]);
            float4 w4 = *reinterpret_cast<const float4*>(&Ws[kk][tx * 4]);
            float a[4] = {a4.x, a4.y, a4.z, a4.w};
            float w[4] = {w4.x, w4.y, w4.z, w4.w};
#pragma unroll
            for (int i = 0; i < 4; ++i)
#pragma unroll
                for (int j = 0; j < 4; ++j)
                    acc[i][j] = fmaf(a[i], w[j], acc[i][j]);
        }
    }
#pragma unroll
    for (int i = 0; i < 4; ++i) {
        int row = m0 + ty * 4 + i;
        if (row >= M) continue;
#pragma unroll
        for (int j = 0; j < 4; ++j) {
            int col = n0 + tx * 4 + j;
            float v = acc[i][j] + bias[col];
            if (ACT == 1) v = fmaxf(v, 0.f);
            C[(size_t)row * N + col] = v;
        }
    }
}

// ---------------------------------------------------------------------------
// Head: out[n] = sigmoid( dot(h2[n], W3) + b3 ).  One wave per node,
// lane l handles h2[n][4l..4l+3] (K=256 = 64 lanes * 4), shuffle reduce.
// ---------------------------------------------------------------------------
__global__ __launch_bounds__(256)
void head_kernel(const float* __restrict__ h2, const float* __restrict__ W3,
                 const float* __restrict__ b3, float* __restrict__ out, int M) {
    int wave = threadIdx.x >> 6;
    int lane = threadIdx.x & 63;
    int n = blockIdx.x * 4 + wave;
    if (n >= M) return;
    float4 h = *reinterpret_cast<const float4*>(h2 + (size_t)n * H_DIM + lane * 4);
    float4 w = *reinterpret_cast<const float4*>(W3 + lane * 4);
    float dot = h.x * w.x + h.y * w.y + h.z * w.z + h.w * w.w;
#pragma unroll
    for (int off = 32; off > 0; off >>= 1) dot += __shfl_down(dot, off);
    if (lane == 0) {
        float v = dot + b3[0];
        out[n] = 1.0f / (1.0f + expf(-v));
    }
}

extern "C" void kernel_launch(void* const* d_in, const int* in_sizes, int n_in,
                              void* d_out, int out_size, void* d_ws, size_t ws_size,
                              hipStream_t stream) {
    const float* x      = (const float*)d_in[0];
    const int*   ei     = (const int*)d_in[1];   // [2, E] row-major: src row then dst row
    const float* W_rel  = (const float*)d_in[2];
    const float* b_rel  = (const float*)d_in[3];
    const float* W_root = (const float*)d_in[4];
    const float* W1     = (const float*)d_in[5];
    const float* b1     = (const float*)d_in[6];
    const float* W2     = (const float*)d_in[7];
    const float* b2     = (const float*)d_in[8];
    const float* W3     = (const float*)d_in[9];
    const float* b3     = (const float*)d_in[10];
    float* out = (float*)d_out;
    const int E = in_sizes[1] / 2;

    // Workspace layout (fp32): agg[10000,128] h0[10000,128] h1/h2[10000,256]
    float* agg = (float*)d_ws;
    float* h0  = agg + (size_t)N_NODES * D_IN;
    float* h1  = h0  + (size_t)N_NODES * D_IN;
    float* h2  = h1  + (size_t)N_NODES * H_DIM;

    hipMemsetAsync(agg, 0, (size_t)N_NODES * D_IN * sizeof(float), stream);

    {   // scatter-add aggregation
        int threads = E * 32;
        scatter_add_kernel<<<(threads + 255) / 256, 256, 0, stream>>>(x, ei, agg, E);
    }
    {   // GraphConv: h0 = agg@W_rel^T + b_rel + x@W_root^T   (concat-K GEMM)
        dim3 g(D_IN / 64, (N_NODES + 63) / 64);
        gemm_bias_act<0><<<g, 256, 0, stream>>>(agg, x, W_rel, W_root, b_rel, h0,
                                                N_NODES, D_IN, D_IN, D_IN);
    }
    {   // h1 = relu(h0@W1^T + b1)
        dim3 g(H_DIM / 64, (N_NODES + 63) / 64);
        gemm_bias_act<1><<<g, 256, 0, stream>>>(h0, nullptr, W1, nullptr, b1, h1,
                                                N_NODES, H_DIM, D_IN, 0);
    }
    {   // h2 = relu(h1@W2^T + b2)
        dim3 g(H_DIM / 64, (N_NODES + 63) / 64);
        gemm_bias_act<1><<<g, 256, 0, stream>>>(h1, nullptr, W2, nullptr, b2, h2,
                                                N_NODES, H_DIM, H_DIM, 0);
    }
    {   // out = sigmoid(h2@W3^T + b3)
        head_kernel<<<(N_NODES + 3) / 4, 256, 0, stream>>>(h2, W3, b3, out, N_NODES);
    }
}

// Round 2
// 277.877 us; speedup vs baseline: 4.3551x; 4.3551x over previous
//
#include <hip/hip_runtime.h>
#include <cmath>

constexpr int N_NODES = 10000;
constexpr int D_IN = 128;   // GraphConv dim
constexpr int H_DIM = 256;  // MLP hidden

// ---------------------------------------------------------------------------
// Step 1: histogram of destination nodes. 640k int atomics over 10k counters
// (40 KB, L2-resident) instead of 82M float atomics over feature rows.
// ---------------------------------------------------------------------------
__global__ __launch_bounds__(256)
void hist_kernel(const int* __restrict__ ei, int* __restrict__ deg, int E) {
    int e = blockIdx.x * blockDim.x + threadIdx.x;
    if (e < E) atomicAdd(&deg[ei[E + e]], 1);
}

// ---------------------------------------------------------------------------
// Step 2: exclusive prefix sum over deg[0..n) -> offsets[0..n], cursor copy.
// Single block, 1024 threads x 10 elems each; Hillis-Steele scan in LDS.
// ---------------------------------------------------------------------------
constexpr int SCAN_NT = 1024, SCAN_CH = 10;
__global__ __launch_bounds__(1024)
void scan_kernel(const int* __restrict__ deg, int* __restrict__ offsets,
                 int* __restrict__ cursor, int n) {
    __shared__ int lds[SCAN_NT];
    const int t = threadIdx.x;
    const int base = t * SCAN_CH;
    int v[SCAN_CH];
    int sum = 0;
    for (int j = 0; j < SCAN_CH; ++j) {
        int idx = base + j;
        int d = (idx < n) ? deg[idx] : 0;
        v[j] = sum;  // exclusive within chunk
        sum += d;
    }
    lds[t] = sum;
    __syncthreads();
    for (int off = 1; off < SCAN_NT; off <<= 1) {
        int other = (t >= off) ? lds[t - off] : 0;
        __syncthreads();
        lds[t] += other;
        __syncthreads();
    }
    int excl = lds[t] - sum;  // exclusive prefix of this chunk
    for (int j = 0; j < SCAN_CH; ++j) {
        int idx = base + j;
        int val = excl + v[j];
        if (idx < n) { offsets[idx] = val; cursor[idx] = val; }
        else if (idx == n) offsets[n] = val;  // total edge count
    }
}

// ---------------------------------------------------------------------------
// Step 3: counting-sort scatter — place each edge's src into its dst's CSR
// slot. 640k int atomics (slot cursors) + 640k coalesced-ish 4B writes.
// ---------------------------------------------------------------------------
__global__ __launch_bounds__(256)
void sort_kernel(const int* __restrict__ ei, int* __restrict__ cursor,
                 int* __restrict__ sorted_src, int E) {
    int e = blockIdx.x * blockDim.x + threadIdx.x;
    if (e < E) {
        int pos = atomicAdd(&cursor[ei[E + e]], 1);
        sorted_src[pos] = ei[e];
    }
}

// ---------------------------------------------------------------------------
// Step 4: per-node gather-sum. One wave per node; lane = (r, c) with
// r = edge-parity (2 edges in flight), c = float4 chunk of the 128-col row.
// x rows are 512 B contiguous -> fully coalesced 16 B/lane loads from L2/L3.
// No atomics; unconditional full-row write (degree-0 nodes write zeros).
// ---------------------------------------------------------------------------
__global__ __launch_bounds__(256)
void gather_sum_kernel(const float* __restrict__ x,
                       const int* __restrict__ offsets,
                       const int* __restrict__ sorted_src,
                       float* __restrict__ agg, int M) {
    int wid = (blockIdx.x * blockDim.x + threadIdx.x) >> 6;
    if (wid >= M) return;
    int lane = threadIdx.x & 63;
    int c = (lane & 31) * 4;
    int r = lane >> 5;
    int beg = offsets[wid], end = offsets[wid + 1];
    float4 acc = {0.f, 0.f, 0.f, 0.f};
    for (int i = beg + r; i < end; i += 2) {
        int s = sorted_src[i];
        const float4 v = *reinterpret_cast<const float4*>(x + (size_t)s * D_IN + c);
        acc.x += v.x; acc.y += v.y; acc.z += v.z; acc.w += v.w;
    }
    acc.x += __shfl_xor(acc.x, 32);
    acc.y += __shfl_xor(acc.y, 32);
    acc.z += __shfl_xor(acc.z, 32);
    acc.w += __shfl_xor(acc.w, 32);
    if (r == 0)
        *reinterpret_cast<float4*>(agg + (size_t)wid * D_IN + c) = acc;
}

// ---------------------------------------------------------------------------
// C[M,N] = act( A@W^T + bias ), A row-major [M,K], W row-major [N,K].
// Concat-K support for the GraphConv layer: A = [A1(K1) | A2(K2)],
// W = [Wa(K1) | Wb(K2)]. Tiles: BM=BN=64, BK=16, 256 threads, 4x4 microtile.
// ---------------------------------------------------------------------------
template <int ACT>  // 0 = none, 1 = relu
__global__ __launch_bounds__(256)
void gemm_bias_act(const float* __restrict__ A1, const float* __restrict__ A2,
                   const float* __restrict__ Wa, const float* __restrict__ Wb,
                   const float* __restrict__ bias, float* __restrict__ C,
                   int M, int N, int K1, int K2) {
    constexpr int BM = 64, BN = 64, BK = 16;
    __shared__ float As[BK][BM + 4];
    __shared__ float Ws[BK][BN + 4];
    const int t = threadIdx.x;
    const int m0 = blockIdx.y * BM;
    const int n0 = blockIdx.x * BN;
    const int tx = t & 15;
    const int ty = t >> 4;
    const int lr = t >> 2;
    const int lk = (t & 3) * 4;
    float acc[4][4] = {};
    const int Ktot = K1 + K2;
    for (int k0 = 0; k0 < Ktot; k0 += BK) {
        const float* Ap; const float* Wp; int kbase, ld;
        if (k0 < K1) { Ap = A1; Wp = Wa; kbase = k0;      ld = K1; }
        else         { Ap = A2; Wp = Wb; kbase = k0 - K1; ld = K2; }
        int row = m0 + lr;
        int rclamp = row < M ? row : M - 1;  // stores are guarded later
        float4 av = *reinterpret_cast<const float4*>(Ap + (size_t)rclamp * ld + kbase + lk);
        float4 wv = *reinterpret_cast<const float4*>(Wp + (size_t)(n0 + lr) * ld + kbase + lk);
        __syncthreads();
        As[lk + 0][lr] = av.x; As[lk + 1][lr] = av.y;
        As[lk + 2][lr] = av.z; As[lk + 3][lr] = av.w;
        Ws[lk + 0][lr] = wv.x; Ws[lk + 1][lr] = wv.y;
        Ws[lk + 2][lr] = wv.z; Ws[lk + 3][lr] = wv.w;
        __syncthreads();
#pragma unroll
        for (int kk = 0; kk < BK; ++kk) {
            float4 a4 = *reinterpret_cast<const float4*>(&As[kk][ty * 4]);
            float4 w4 = *reinterpret_cast<const float4*>(&Ws[kk][tx * 4]);
            float a[4] = {a4.x, a4.y, a4.z, a4.w};
            float w[4] = {w4.x, w4.y, w4.z, w4.w};
#pragma unroll
            for (int i = 0; i < 4; ++i)
#pragma unroll
                for (int j = 0; j < 4; ++j)
                    acc[i][j] = fmaf(a[i], w[j], acc[i][j]);
        }
    }
#pragma unroll
    for (int i = 0; i < 4; ++i) {
        int row = m0 + ty * 4 + i;
        if (row >= M) continue;
#pragma unroll
        for (int j = 0; j < 4; ++j) {
            int col = n0 + tx * 4 + j;
            float v = acc[i][j] + bias[col];
            if (ACT == 1) v = fmaxf(v, 0.f);
            C[(size_t)row * N + col] = v;
        }
    }
}

// ---------------------------------------------------------------------------
// Head: out[n] = sigmoid( dot(h2[n], W3) + b3 ). One wave per node.
// ---------------------------------------------------------------------------
__global__ __launch_bounds__(256)
void head_kernel(const float* __restrict__ h2, const float* __restrict__ W3,
                 const float* __restrict__ b3, float* __restrict__ out, int M) {
    int wave = threadIdx.x >> 6;
    int lane = threadIdx.x & 63;
    int n = blockIdx.x * 4 + wave;
    if (n >= M) return;
    float4 h = *reinterpret_cast<const float4*>(h2 + (size_t)n * H_DIM + lane * 4);
    float4 w = *reinterpret_cast<const float4*>(W3 + lane * 4);
    float dot = h.x * w.x + h.y * w.y + h.z * w.z + h.w * w.w;
#pragma unroll
    for (int off = 32; off > 0; off >>= 1) dot += __shfl_down(dot, off);
    if (lane == 0) {
        float v = dot + b3[0];
        out[n] = 1.0f / (1.0f + expf(-v));
    }
}

extern "C" void kernel_launch(void* const* d_in, const int* in_sizes, int n_in,
                              void* d_out, int out_size, void* d_ws, size_t ws_size,
                              hipStream_t stream) {
    const float* x      = (const float*)d_in[0];
    const int*   ei     = (const int*)d_in[1];   // [2, E]: src row then dst row
    const float* W_rel  = (const float*)d_in[2];
    const float* b_rel  = (const float*)d_in[3];
    const float* W_root = (const float*)d_in[4];
    const float* W1     = (const float*)d_in[5];
    const float* b1     = (const float*)d_in[6];
    const float* W2     = (const float*)d_in[7];
    const float* b2     = (const float*)d_in[8];
    const float* W3     = (const float*)d_in[9];
    const float* b3     = (const float*)d_in[10];
    float* out = (float*)d_out;
    const int E = in_sizes[1] / 2;

    // Workspace (30.7 MB, same footprint as the passing R1 layout):
    //   agg[10000,128] | h0[10000,128] | h1[10000,256] | h2[10000,256]
    // CSR scratch aliases regions that are dead during aggregation:
    //   sorted_src (2.56 MB) aliases h1; offsets/cursor/deg (120 KB) alias h2.
    // Stream order: CSR built+consumed (gather) before gemm1 writes h1 and
    // gemm2 writes h2 — no overlap of live ranges.
    float* agg = (float*)d_ws;
    float* h0  = agg + (size_t)N_NODES * D_IN;
    float* h1  = h0  + (size_t)N_NODES * D_IN;
    float* h2  = h1  + (size_t)N_NODES * H_DIM;
    int* sorted_src = (int*)h1;
    int* offsets    = (int*)h2;                 // 10001 ints
    int* cursor     = offsets + N_NODES + 2;    // 10000 ints
    int* deg        = cursor + N_NODES;         // 10000 ints

    hipMemsetAsync(deg, 0, N_NODES * sizeof(int), stream);
    hist_kernel<<<(E + 255) / 256, 256, 0, stream>>>(ei, deg, E);
    scan_kernel<<<1, SCAN_NT, 0, stream>>>(deg, offsets, cursor, N_NODES);
    sort_kernel<<<(E + 255) / 256, 256, 0, stream>>>(ei, cursor, sorted_src, E);
    gather_sum_kernel<<<(N_NODES * 64 + 255) / 256, 256, 0, stream>>>(
        x, offsets, sorted_src, agg, N_NODES);

    {   // GraphConv: h0 = agg@W_rel^T + b_rel + x@W_root^T   (concat-K GEMM)
        dim3 g(D_IN / 64, (N_NODES + 63) / 64);
        gemm_bias_act<0><<<g, 256, 0, stream>>>(agg, x, W_rel, W_root, b_rel, h0,
                                                N_NODES, D_IN, D_IN, D_IN);
    }
    {   // h1 = relu(h0@W1^T + b1)
        dim3 g(H_DIM / 64, (N_NODES + 63) / 64);
        gemm_bias_act<1><<<g, 256, 0, stream>>>(h0, nullptr, W1, nullptr, b1, h1,
                                                N_NODES, H_DIM, D_IN, 0);
    }
    {   // h2 = relu(h1@W2^T + b2)
        dim3 g(H_DIM / 64, (N_NODES + 63) / 64);
        gemm_bias_act<1><<<g, 256, 0, stream>>>(h1, nullptr, W2, nullptr, b2, h2,
                                                N_NODES, H_DIM, H_DIM, 0);
    }
    head_kernel<<<(N_NODES + 3) / 4, 256, 0, stream>>>(h2, W3, b3, out, N_NODES);
}

// Round 3
// 262.426 us; speedup vs baseline: 4.6115x; 1.0589x over previous
//
#include <hip/hip_runtime.h>
#include <cmath>

constexpr int N_NODES = 10000;
constexpr int D_IN = 128;   // GraphConv dim
constexpr int H_DIM = 256;  // MLP hidden

// ---------------------------------------------------------------------------
// Step 1: histogram of destination nodes (int atomics over 40 KB L2-resident).
// ---------------------------------------------------------------------------
__global__ __launch_bounds__(256)
void hist_kernel(const int* __restrict__ ei, int* __restrict__ deg, int E) {
    int e = blockIdx.x * blockDim.x + threadIdx.x;
    if (e < E) atomicAdd(&deg[ei[E + e]], 1);
}

// ---------------------------------------------------------------------------
// Step 2: exclusive prefix sum over deg[0..n) -> offsets[0..n] + cursor copy.
// 256 threads x 40 elems; wave shuffle scan (no-barrier) + 4-entry LDS merge.
// ---------------------------------------------------------------------------
constexpr int SCAN_NT = 256, SCAN_CH = 40;  // covers 10240 >= 10001
__global__ __launch_bounds__(256)
void scan_kernel(const int* __restrict__ deg, int* __restrict__ offsets,
                 int* __restrict__ cursor, int n) {
    __shared__ int wsum[4];
    const int t = threadIdx.x;
    const int lane = t & 63, wv = t >> 6;
    const int base = t * SCAN_CH;
    int v[SCAN_CH];
    int sum = 0;
    for (int j = 0; j < SCAN_CH; ++j) {
        int idx = base + j;
        int d = (idx < n) ? deg[idx] : 0;
        v[j] = sum;  // exclusive within chunk
        sum += d;
    }
    int incl = sum;  // inclusive wave scan of per-thread sums
#pragma unroll
    for (int off = 1; off < 64; off <<= 1) {
        int o = __shfl_up(incl, off);
        if (lane >= off) incl += o;
    }
    if (lane == 63) wsum[wv] = incl;
    __syncthreads();
    int wbase = 0;
#pragma unroll
    for (int w = 0; w < 4; ++w)
        if (w < wv) wbase += wsum[w];
    const int excl = wbase + incl - sum;  // exclusive prefix of this chunk
    for (int j = 0; j < SCAN_CH; ++j) {
        int idx = base + j;
        int val = excl + v[j];
        if (idx < n) { offsets[idx] = val; cursor[idx] = val; }
        else if (idx == n) offsets[n] = val;
    }
}

// ---------------------------------------------------------------------------
// Step 3: counting-sort scatter — edge src into its dst's CSR slot.
// ---------------------------------------------------------------------------
__global__ __launch_bounds__(256)
void sort_kernel(const int* __restrict__ ei, int* __restrict__ cursor,
                 int* __restrict__ sorted_src, int E) {
    int e = blockIdx.x * blockDim.x + threadIdx.x;
    if (e < E) {
        int pos = atomicAdd(&cursor[ei[E + e]], 1);
        sorted_src[pos] = ei[e];
    }
}

// ---------------------------------------------------------------------------
// Step 4: per-node gather-sum, ILP x4. One wave per node; half-wave r takes a
// CONTIGUOUS half of the node's edge range (so 4 consecutive src indices can
// be batch-loaded), 32 col-lanes x float4 cover the 128-float row. 4 pending
// x-row loads per iteration hide the ~300-600 cyc L2/L3 latency that bounded
// R2's single-chain version (VALUBusy 9.5%).
// ---------------------------------------------------------------------------
__global__ __launch_bounds__(256)
void gather_sum_kernel(const float* __restrict__ x,
                       const int* __restrict__ offsets,
                       const int* __restrict__ sorted_src,
                       float* __restrict__ agg, int M) {
    int wid = (blockIdx.x * blockDim.x + threadIdx.x) >> 6;
    if (wid >= M) return;
    int lane = threadIdx.x & 63;
    int c = (lane & 31) * 4;
    int r = lane >> 5;
    int beg = offsets[wid], end = offsets[wid + 1];
    int half = (end - beg + 1) >> 1;
    int i = r ? beg + half : beg;
    const int i1 = r ? end : beg + half;
    float4 a0 = {0, 0, 0, 0}, a1 = {0, 0, 0, 0}, a2 = {0, 0, 0, 0}, a3 = {0, 0, 0, 0};
    for (; i + 4 <= i1; i += 4) {
        int s0 = sorted_src[i + 0], s1 = sorted_src[i + 1];
        int s2 = sorted_src[i + 2], s3 = sorted_src[i + 3];
        const float4 v0 = *reinterpret_cast<const float4*>(x + (size_t)s0 * D_IN + c);
        const float4 v1 = *reinterpret_cast<const float4*>(x + (size_t)s1 * D_IN + c);
        const float4 v2 = *reinterpret_cast<const float4*>(x + (size_t)s2 * D_IN + c);
        const float4 v3 = *reinterpret_cast<const float4*>(x + (size_t)s3 * D_IN + c);
        a0.x += v0.x; a0.y += v0.y; a0.z += v0.z; a0.w += v0.w;
        a1.x += v1.x; a1.y += v1.y; a1.z += v1.z; a1.w += v1.w;
        a2.x += v2.x; a2.y += v2.y; a2.z += v2.z; a2.w += v2.w;
        a3.x += v3.x; a3.y += v3.y; a3.z += v3.z; a3.w += v3.w;
    }
    for (; i < i1; ++i) {
        int s = sorted_src[i];
        const float4 v = *reinterpret_cast<const float4*>(x + (size_t)s * D_IN + c);
        a0.x += v.x; a0.y += v.y; a0.z += v.z; a0.w += v.w;
    }
    a0.x += a1.x + a2.x + a3.x;
    a0.y += a1.y + a2.y + a3.y;
    a0.z += a1.z + a2.z + a3.z;
    a0.w += a1.w + a2.w + a3.w;
    a0.x += __shfl_xor(a0.x, 32);
    a0.y += __shfl_xor(a0.y, 32);
    a0.z += __shfl_xor(a0.z, 32);
    a0.w += __shfl_xor(a0.w, 32);
    if (r == 0)
        *reinterpret_cast<float4*>(agg + (size_t)wid * D_IN + c) = a0;
}

// ---------------------------------------------------------------------------
// C[M,N] = act( A@W^T + bias ), A row-major [M,K], W row-major [N,K].
// Concat-K: A = [A1(K1) | A2(K2)], W = [Wa(K1) | Wb(K2)], BK | K1,K2.
// BM=BN=64, BK=32, 256 threads, 4x4 microtile, register prefetch of the next
// tile overlapping compute. LDS writes keep the verified conflict-free
// pattern: k-offset (t&3)*4 with stride 68 -> 2 lanes/bank (free per m136).
// ---------------------------------------------------------------------------
template <int ACT>  // 0 = none, 1 = relu
__global__ __launch_bounds__(256)
void gemm_bias_act(const float* __restrict__ A1, const float* __restrict__ A2,
                   const float* __restrict__ Wa, const float* __restrict__ Wb,
                   const float* __restrict__ bias, float* __restrict__ C,
                   int M, int N, int K1, int K2) {
    constexpr int BM = 64, BN = 64, BK = 32;
    __shared__ float As[BK][BM + 4];
    __shared__ float Ws[BK][BN + 4];
    const int t = threadIdx.x;
    const int m0 = blockIdx.y * BM;
    const int n0 = blockIdx.x * BN;
    const int tx = t & 15, ty = t >> 4;
    const int lr = t >> 2, lka = (t & 3) * 4;
    const int Ktot = K1 + K2;
    const int arow = (m0 + lr < M) ? m0 + lr : M - 1;  // stores guarded below
    float4 av0, av1, wv0, wv1;
    auto load_tile = [&](int k0) {
        const float* Ap; const float* Wp; int kb, ld;
        if (k0 < K1) { Ap = A1; Wp = Wa; kb = k0;      ld = K1; }
        else         { Ap = A2; Wp = Wb; kb = k0 - K1; ld = K2; }
        const float* ar = Ap + (size_t)arow * ld + kb;
        const float* wr = Wp + (size_t)(n0 + lr) * ld + kb;
        av0 = *reinterpret_cast<const float4*>(ar + lka);
        av1 = *reinterpret_cast<const float4*>(ar + 16 + lka);
        wv0 = *reinterpret_cast<const float4*>(wr + lka);
        wv1 = *reinterpret_cast<const float4*>(wr + 16 + lka);
    };
    float acc[4][4] = {};
    load_tile(0);
    for (int k0 = 0; k0 < Ktot; k0 += BK) {
        __syncthreads();  // previous iteration's LDS readers done
        As[lka + 0][lr] = av0.x; As[lka + 1][lr] = av0.y;
        As[lka + 2][lr] = av0.z; As[lka + 3][lr] = av0.w;
        As[16 + lka + 0][lr] = av1.x; As[16 + lka + 1][lr] = av1.y;
        As[16 + lka + 2][lr] = av1.z; As[16 + lka + 3][lr] = av1.w;
        Ws[lka + 0][lr] = wv0.x; Ws[lka + 1][lr] = wv0.y;
        Ws[lka + 2][lr] = wv0.z; Ws[lka + 3][lr] = wv0.w;
        Ws[16 + lka + 0][lr] = wv1.x; Ws[16 + lka + 1][lr] = wv1.y;
        Ws[16 + lka + 2][lr] = wv1.z; Ws[16 + lka + 3][lr] = wv1.w;
        __syncthreads();
        if (k0 + BK < Ktot) load_tile(k0 + BK);  // prefetch overlaps compute
#pragma unroll
        for (int kk = 0; kk < BK; ++kk) {
            float4 a4 = *reinterpret_cast<const float4*>(&As[kk][ty * 4]);
            float4 w4 = *reinterpret_cast<const float4*>(&Ws[kk][tx * 4]);
            float a[4] = {a4.x, a4.y, a4.z, a4.w};
            float w[4] = {w4.x, w4.y, w4.z, w4.w};
#pragma unroll
            for (int i = 0; i < 4; ++i)
#pragma unroll
                for (int j = 0; j < 4; ++j)
                    acc[i][j] = fmaf(a[i], w[j], acc[i][j]);
        }
    }
#pragma unroll
    for (int i = 0; i < 4; ++i) {
        int row = m0 + ty * 4 + i;
        if (row >= M) continue;
#pragma unroll
        for (int j = 0; j < 4; ++j) {
            int col = n0 + tx * 4 + j;
            float v = acc[i][j] + bias[col];
            if (ACT == 1) v = fmaxf(v, 0.f);
            C[(size_t)row * N + col] = v;
        }
    }
}

// ---------------------------------------------------------------------------
// Head: out[n] = sigmoid( dot(h2[n], W3) + b3 ). One wave per node.
// ---------------------------------------------------------------------------
__global__ __launch_bounds__(256)
void head_kernel(const float* __restrict__ h2, const float* __restrict__ W3,
                 const float* __restrict__ b3, float* __restrict__ out, int M) {
    int wave = threadIdx.x >> 6;
    int lane = threadIdx.x & 63;
    int n = blockIdx.x * 4 + wave;
    if (n >= M) return;
    float4 h = *reinterpret_cast<const float4*>(h2 + (size_t)n * H_DIM + lane * 4);
    float4 w = *reinterpret_cast<const float4*>(W3 + lane * 4);
    float dot = h.x * w.x + h.y * w.y + h.z * w.z + h.w * w.w;
#pragma unroll
    for (int off = 32; off > 0; off >>= 1) dot += __shfl_down(dot, off);
    if (lane == 0) {
        float v = dot + b3[0];
        out[n] = 1.0f / (1.0f + expf(-v));
    }
}

extern "C" void kernel_launch(void* const* d_in, const int* in_sizes, int n_in,
                              void* d_out, int out_size, void* d_ws, size_t ws_size,
                              hipStream_t stream) {
    const float* x      = (const float*)d_in[0];
    const int*   ei     = (const int*)d_in[1];   // [2, E]: src row then dst row
    const float* W_rel  = (const float*)d_in[2];
    const float* b_rel  = (const float*)d_in[3];
    const float* W_root = (const float*)d_in[4];
    const float* W1     = (const float*)d_in[5];
    const float* b1     = (const float*)d_in[6];
    const float* W2     = (const float*)d_in[7];
    const float* b2     = (const float*)d_in[8];
    const float* W3     = (const float*)d_in[9];
    const float* b3     = (const float*)d_in[10];
    float* out = (float*)d_out;
    const int E = in_sizes[1] / 2;

    // Workspace: agg[10000,128] | h0[10000,128] | h1[10000,256] | h2[10000,256]
    // CSR scratch aliases regions dead during aggregation (sorted_src -> h1,
    // offsets/cursor/deg -> h2); stream order keeps live ranges disjoint.
    float* agg = (float*)d_ws;
    float* h0  = agg + (size_t)N_NODES * D_IN;
    float* h1  = h0  + (size_t)N_NODES * D_IN;
    float* h2  = h1  + (size_t)N_NODES * H_DIM;
    int* sorted_src = (int*)h1;
    int* offsets    = (int*)h2;                 // 10001 ints
    int* cursor     = offsets + N_NODES + 2;    // 10000 ints
    int* deg        = cursor + N_NODES;         // 10000 ints

    hipMemsetAsync(deg, 0, N_NODES * sizeof(int), stream);
    hist_kernel<<<(E + 255) / 256, 256, 0, stream>>>(ei, deg, E);
    scan_kernel<<<1, SCAN_NT, 0, stream>>>(deg, offsets, cursor, N_NODES);
    sort_kernel<<<(E + 255) / 256, 256, 0, stream>>>(ei, cursor, sorted_src, E);
    gather_sum_kernel<<<(N_NODES * 64 + 255) / 256, 256, 0, stream>>>(
        x, offsets, sorted_src, agg, N_NODES);

    {   // GraphConv: h0 = agg@W_rel^T + b_rel + x@W_root^T   (concat-K GEMM)
        dim3 g(D_IN / 64, (N_NODES + 63) / 64);
        gemm_bias_act<0><<<g, 256, 0, stream>>>(agg, x, W_rel, W_root, b_rel, h0,
                                                N_NODES, D_IN, D_IN, D_IN);
    }
    {   // h1 = relu(h0@W1^T + b1)
        dim3 g(H_DIM / 64, (N_NODES + 63) / 64);
        gemm_bias_act<1><<<g, 256, 0, stream>>>(h0, nullptr, W1, nullptr, b1, h1,
                                                N_NODES, H_DIM, D_IN, 0);
    }
    {   // h2 = relu(h1@W2^T + b2)
        dim3 g(H_DIM / 64, (N_NODES + 63) / 64);
        gemm_bias_act<1><<<g, 256, 0, stream>>>(h1, nullptr, W2, nullptr, b2, h2,
                                                N_NODES, H_DIM, H_DIM, 0);
    }
    head_kernel<<<(N_NODES + 3) / 4, 256, 0, stream>>>(h2, W3, b3, out, N_NODES);
}

// Round 4
// 226.515 us; speedup vs baseline: 5.3426x; 1.1585x over previous
//
#include <hip/hip_runtime.h>
#include <hip/hip_bf16.h>
#include <cmath>

constexpr int N_NODES = 10000;
constexpr int D_IN = 128;   // GraphConv dim
constexpr int H_DIM = 256;  // MLP hidden

typedef unsigned short u16;
typedef short bf16x8 __attribute__((ext_vector_type(8)));  // 8 bf16 = 4 VGPRs
typedef float f32x4 __attribute__((ext_vector_type(4)));

__device__ inline u16 f2bf(float f) {
    return __builtin_bit_cast(u16, __float2bfloat16(f));  // RNE hw cvt
}
__device__ inline float bf2f(u16 u) {
    unsigned int v = (unsigned int)u << 16;
    return __builtin_bit_cast(float, v);
}

// ---------------------------------------------------------------------------
// Step 1: histogram of destination nodes (int atomics over 40 KB L2-resident).
// ---------------------------------------------------------------------------
__global__ __launch_bounds__(256)
void hist_kernel(const int* __restrict__ ei, int* __restrict__ deg, int E) {
    int e = blockIdx.x * blockDim.x + threadIdx.x;
    if (e < E) atomicAdd(&deg[ei[E + e]], 1);
}

// ---------------------------------------------------------------------------
// Step 2: exclusive prefix sum deg -> offsets[0..n] + cursor copy.
// 256 threads x 40 elems; wave shuffle scan + 4-entry LDS merge.
// ---------------------------------------------------------------------------
constexpr int SCAN_NT = 256, SCAN_CH = 40;  // covers 10240 >= 10001
__global__ __launch_bounds__(256)
void scan_kernel(const int* __restrict__ deg, int* __restrict__ offsets,
                 int* __restrict__ cursor, int n) {
    __shared__ int wsum[4];
    const int t = threadIdx.x;
    const int lane = t & 63, wv = t >> 6;
    const int base = t * SCAN_CH;
    int v[SCAN_CH];
    int sum = 0;
    for (int j = 0; j < SCAN_CH; ++j) {
        int idx = base + j;
        int d = (idx < n) ? deg[idx] : 0;
        v[j] = sum;
        sum += d;
    }
    int incl = sum;
#pragma unroll
    for (int off = 1; off < 64; off <<= 1) {
        int o = __shfl_up(incl, off);
        if (lane >= off) incl += o;
    }
    if (lane == 63) wsum[wv] = incl;
    __syncthreads();
    int wbase = 0;
#pragma unroll
    for (int w = 0; w < 4; ++w)
        if (w < wv) wbase += wsum[w];
    const int excl = wbase + incl - sum;
    for (int j = 0; j < SCAN_CH; ++j) {
        int idx = base + j;
        int val = excl + v[j];
        if (idx < n) { offsets[idx] = val; cursor[idx] = val; }
        else if (idx == n) offsets[n] = val;
    }
}

// ---------------------------------------------------------------------------
// Step 3: counting-sort scatter — edge src into its dst's CSR slot.
// ---------------------------------------------------------------------------
__global__ __launch_bounds__(256)
void sort_kernel(const int* __restrict__ ei, int* __restrict__ cursor,
                 int* __restrict__ sorted_src, int E) {
    int e = blockIdx.x * blockDim.x + threadIdx.x;
    if (e < E) {
        int pos = atomicAdd(&cursor[ei[E + e]], 1);
        sorted_src[pos] = ei[e];
    }
}

// ---------------------------------------------------------------------------
// Step 4: per-node gather-sum, ILP x4, fp32 accumulate, bf16 output written
// directly into A0 = [agg_bf | x_bf] rows (stride 256, offset 0).
// ---------------------------------------------------------------------------
__global__ __launch_bounds__(256)
void gather_sum_kernel(const float* __restrict__ x,
                       const int* __restrict__ offsets,
                       const int* __restrict__ sorted_src,
                       u16* __restrict__ A0, int M) {
    int wid = (blockIdx.x * blockDim.x + threadIdx.x) >> 6;
    if (wid >= M) return;
    int lane = threadIdx.x & 63;
    int c = (lane & 31) * 4;
    int r = lane >> 5;
    int beg = offsets[wid], end = offsets[wid + 1];
    int half = (end - beg + 1) >> 1;
    int i = r ? beg + half : beg;
    const int i1 = r ? end : beg + half;
    float4 a0 = {0, 0, 0, 0}, a1 = {0, 0, 0, 0}, a2 = {0, 0, 0, 0}, a3 = {0, 0, 0, 0};
    for (; i + 4 <= i1; i += 4) {
        int s0 = sorted_src[i + 0], s1 = sorted_src[i + 1];
        int s2 = sorted_src[i + 2], s3 = sorted_src[i + 3];
        const float4 v0 = *reinterpret_cast<const float4*>(x + (size_t)s0 * D_IN + c);
        const float4 v1 = *reinterpret_cast<const float4*>(x + (size_t)s1 * D_IN + c);
        const float4 v2 = *reinterpret_cast<const float4*>(x + (size_t)s2 * D_IN + c);
        const float4 v3 = *reinterpret_cast<const float4*>(x + (size_t)s3 * D_IN + c);
        a0.x += v0.x; a0.y += v0.y; a0.z += v0.z; a0.w += v0.w;
        a1.x += v1.x; a1.y += v1.y; a1.z += v1.z; a1.w += v1.w;
        a2.x += v2.x; a2.y += v2.y; a2.z += v2.z; a2.w += v2.w;
        a3.x += v3.x; a3.y += v3.y; a3.z += v3.z; a3.w += v3.w;
    }
    for (; i < i1; ++i) {
        int s = sorted_src[i];
        const float4 v = *reinterpret_cast<const float4*>(x + (size_t)s * D_IN + c);
        a0.x += v.x; a0.y += v.y; a0.z += v.z; a0.w += v.w;
    }
    a0.x += a1.x + a2.x + a3.x;
    a0.y += a1.y + a2.y + a3.y;
    a0.z += a1.z + a2.z + a3.z;
    a0.w += a1.w + a2.w + a3.w;
    a0.x += __shfl_xor(a0.x, 32);
    a0.y += __shfl_xor(a0.y, 32);
    a0.z += __shfl_xor(a0.z, 32);
    a0.w += __shfl_xor(a0.w, 32);
    if (r == 0) {
        ushort4 o;
        o.x = f2bf(a0.x); o.y = f2bf(a0.y); o.z = f2bf(a0.z); o.w = f2bf(a0.w);
        *reinterpret_cast<ushort4*>(A0 + (size_t)wid * 256 + c) = o;
    }
}

// ---------------------------------------------------------------------------
// Cast x (fp32 [10000,128]) into A0 rows' second half (bf16, stride 256).
// ---------------------------------------------------------------------------
__global__ __launch_bounds__(256)
void cast_x_kernel(const float* __restrict__ x, u16* __restrict__ A0, int total4) {
    int idx = blockIdx.x * blockDim.x + threadIdx.x;
    if (idx >= total4) return;
    int row = idx >> 5;            // 32 float4-chunks per 128-col row
    int c = (idx & 31) * 4;
    float4 v = *reinterpret_cast<const float4*>(x + (size_t)row * D_IN + c);
    ushort4 o;
    o.x = f2bf(v.x); o.y = f2bf(v.y); o.z = f2bf(v.z); o.w = f2bf(v.w);
    *reinterpret_cast<ushort4*>(A0 + (size_t)row * 256 + 128 + c) = o;
}

// ---------------------------------------------------------------------------
// Cast weights to bf16: Wcat[128][256] = [W_rel | W_root], W1b[256][128],
// W2b[256][256]. One kernel, region by flat index (all float4-aligned).
// ---------------------------------------------------------------------------
__global__ __launch_bounds__(256)
void cast_w_kernel(const float* __restrict__ W_rel, const float* __restrict__ W_root,
                   const float* __restrict__ W1, const float* __restrict__ W2,
                   u16* __restrict__ Wcat, u16* __restrict__ W1b, u16* __restrict__ W2b) {
    int idx4 = (blockIdx.x * blockDim.x + threadIdx.x) * 4;  // 131072 elems total
    const float* src;
    u16* dst;
    if (idx4 < 32768) {            // Wcat
        int n = idx4 >> 8, k = idx4 & 255;
        src = (k < 128) ? W_rel + n * 128 + k : W_root + n * 128 + (k - 128);
        dst = Wcat + idx4;
    } else if (idx4 < 65536) {     // W1
        src = W1 + (idx4 - 32768);
        dst = W1b + (idx4 - 32768);
    } else {                       // W2
        src = W2 + (idx4 - 65536);
        dst = W2b + (idx4 - 65536);
    }
    float4 v = *reinterpret_cast<const float4*>(src);
    ushort4 o;
    o.x = f2bf(v.x); o.y = f2bf(v.y); o.z = f2bf(v.z); o.w = f2bf(v.w);
    *reinterpret_cast<ushort4*>(dst) = o;
}

// ---------------------------------------------------------------------------
// bf16 MFMA GEMM: C[M,N] = act(A@W^T + bias), A bf16 [M,K] rm, W bf16 [N,K] rm
// (W row-major IS the B^T layout the B-fragment wants), C bf16, fp32 acc.
// Block 256 thr = 4 waves (2x2 of 32x32), tile 64x64, BK=64 LDS-staged.
// LDS row stride 80 (160B: 16B-aligned rows; frag-read conflicts <=4-way).
// Frag layouts (m89/m91-verified): A[m=lane&15][k=quad*8+j],
// B[n=lane&15][k=quad*8+j], C/D col=lane&15 row=quad*4+reg.
// ---------------------------------------------------------------------------
template <int ACT>  // 0 = none, 1 = relu
__global__ __launch_bounds__(256)
void mfma_gemm(const u16* __restrict__ A, const u16* __restrict__ W,
               const float* __restrict__ bias, u16* __restrict__ C,
               int M, int N, int K) {
    constexpr int LDT = 80;
    __shared__ short As[64 * LDT];
    __shared__ short Ws[64 * LDT];
    const int t = threadIdx.x;
    const int m0 = blockIdx.y * 64;
    const int n0 = blockIdx.x * 64;
    const int w = t >> 6, lane = t & 63;
    const int wr = w >> 1, wc = w & 1;
    const int m_lane = lane & 15, q = lane >> 4;
    f32x4 acc[2][2] = {};
    for (int k0 = 0; k0 < K; k0 += 64) {
        __syncthreads();  // previous iteration's LDS readers done
#pragma unroll
        for (int L = 0; L < 2; ++L) {
            int idx = t + 256 * L;        // 512 x 8-elem chunks per tile
            int row = idx >> 3;
            int kc = (idx & 7) * 8;
            int ar = m0 + row; if (ar >= M) ar = M - 1;   // stores guarded
            bf16x8 av = *reinterpret_cast<const bf16x8*>(A + (size_t)ar * K + k0 + kc);
            bf16x8 wv = *reinterpret_cast<const bf16x8*>(W + (size_t)(n0 + row) * K + k0 + kc);
            *reinterpret_cast<bf16x8*>(&As[row * LDT + kc]) = av;
            *reinterpret_cast<bf16x8*>(&Ws[row * LDT + kc]) = wv;
        }
        __syncthreads();
#pragma unroll
        for (int kk = 0; kk < 64; kk += 32) {
            const int koff = kk + q * 8;
            bf16x8 af[2], bf[2];
#pragma unroll
            for (int i = 0; i < 2; ++i)
                af[i] = *reinterpret_cast<const bf16x8*>(
                    &As[(wr * 32 + i * 16 + m_lane) * LDT + koff]);
#pragma unroll
            for (int j = 0; j < 2; ++j)
                bf[j] = *reinterpret_cast<const bf16x8*>(
                    &Ws[(wc * 32 + j * 16 + m_lane) * LDT + koff]);
#pragma unroll
            for (int i = 0; i < 2; ++i)
#pragma unroll
                for (int j = 0; j < 2; ++j)
                    acc[i][j] = __builtin_amdgcn_mfma_f32_16x16x32_bf16(
                        af[i], bf[j], acc[i][j], 0, 0, 0);
        }
    }
#pragma unroll
    for (int i = 0; i < 2; ++i)
#pragma unroll
        for (int j = 0; j < 2; ++j) {
            int col = n0 + wc * 32 + j * 16 + m_lane;
            float b = bias[col];
#pragma unroll
            for (int r = 0; r < 4; ++r) {
                int row = m0 + wr * 32 + i * 16 + q * 4 + r;
                if (row >= M) continue;
                float v = acc[i][j][r] + b;
                if (ACT == 1) v = fmaxf(v, 0.f);
                C[(size_t)row * N + col] = f2bf(v);
            }
        }
}

// ---------------------------------------------------------------------------
// Head: out[n] = sigmoid( dot(h2_bf16[n], W3) + b3 ). One wave per node.
// ---------------------------------------------------------------------------
__global__ __launch_bounds__(256)
void head_kernel(const u16* __restrict__ h2, const float* __restrict__ W3,
                 const float* __restrict__ b3, float* __restrict__ out, int M) {
    int wave = threadIdx.x >> 6;
    int lane = threadIdx.x & 63;
    int n = blockIdx.x * 4 + wave;
    if (n >= M) return;
    ushort4 hu = *reinterpret_cast<const ushort4*>(h2 + (size_t)n * H_DIM + lane * 4);
    float4 w = *reinterpret_cast<const float4*>(W3 + lane * 4);
    float dot = bf2f(hu.x) * w.x + bf2f(hu.y) * w.y + bf2f(hu.z) * w.z + bf2f(hu.w) * w.w;
#pragma unroll
    for (int off = 32; off > 0; off >>= 1) dot += __shfl_down(dot, off);
    if (lane == 0) {
        float v = dot + b3[0];
        out[n] = 1.0f / (1.0f + expf(-v));
    }
}

extern "C" void kernel_launch(void* const* d_in, const int* in_sizes, int n_in,
                              void* d_out, int out_size, void* d_ws, size_t ws_size,
                              hipStream_t stream) {
    const float* x      = (const float*)d_in[0];
    const int*   ei     = (const int*)d_in[1];   // [2, E]: src row then dst row
    const float* W_rel  = (const float*)d_in[2];
    const float* b_rel  = (const float*)d_in[3];
    const float* W_root = (const float*)d_in[4];
    const float* W1     = (const float*)d_in[5];
    const float* b1     = (const float*)d_in[6];
    const float* W2     = (const float*)d_in[7];
    const float* b2     = (const float*)d_in[8];
    const float* W3     = (const float*)d_in[9];
    const float* b3     = (const float*)d_in[10];
    float* out = (float*)d_out;
    const int E = in_sizes[1] / 2;

    // Workspace (disjoint, ~21 MB of the >=256 MB ws):
    char* p = (char*)d_ws;
    auto carve = [&](size_t bytes) { char* r = p; p += (bytes + 63) & ~size_t(63); return r; };
    u16* A0   = (u16*)carve((size_t)N_NODES * 256 * 2);  // [agg_bf | x_bf]
    u16* h0   = (u16*)carve((size_t)N_NODES * 128 * 2);
    u16* h1   = (u16*)carve((size_t)N_NODES * 256 * 2);
    u16* h2   = (u16*)carve((size_t)N_NODES * 256 * 2);
    u16* Wcat = (u16*)carve(128 * 256 * 2);
    u16* W1b  = (u16*)carve(256 * 128 * 2);
    u16* W2b  = (u16*)carve(256 * 256 * 2);
    int* offsets    = (int*)carve((N_NODES + 4) * 4);
    int* cursor     = (int*)carve(N_NODES * 4);
    int* deg        = (int*)carve(N_NODES * 4);
    int* sorted_src = (int*)carve((size_t)E * 4);

    hipMemsetAsync(deg, 0, N_NODES * sizeof(int), stream);
    hist_kernel<<<(E + 255) / 256, 256, 0, stream>>>(ei, deg, E);
    scan_kernel<<<1, SCAN_NT, 0, stream>>>(deg, offsets, cursor, N_NODES);
    sort_kernel<<<(E + 255) / 256, 256, 0, stream>>>(ei, cursor, sorted_src, E);
    gather_sum_kernel<<<(N_NODES * 64 + 255) / 256, 256, 0, stream>>>(
        x, offsets, sorted_src, A0, N_NODES);
    cast_x_kernel<<<(N_NODES * 32 + 255) / 256, 256, 0, stream>>>(x, A0, N_NODES * 32);
    cast_w_kernel<<<131072 / 4 / 256, 256, 0, stream>>>(W_rel, W_root, W1, W2,
                                                        Wcat, W1b, W2b);
    {   // GraphConv: h0 = A0 @ Wcat^T + b_rel   (K=256, N=128)
        dim3 g(128 / 64, (N_NODES + 63) / 64);
        mfma_gemm<0><<<g, 256, 0, stream>>>(A0, Wcat, b_rel, h0, N_NODES, 128, 256);
    }
    {   // h1 = relu(h0 @ W1^T + b1)   (K=128, N=256)
        dim3 g(256 / 64, (N_NODES + 63) / 64);
        mfma_gemm<1><<<g, 256, 0, stream>>>(h0, W1b, b1, h1, N_NODES, 256, 128);
    }
    {   // h2 = relu(h1 @ W2^T + b2)   (K=256, N=256)
        dim3 g(256 / 64, (N_NODES + 63) / 64);
        mfma_gemm<1><<<g, 256, 0, stream>>>(h1, W2b, b2, h2, N_NODES, 256, 256);
    }
    head_kernel<<<(N_NODES + 3) / 4, 256, 0, stream>>>(h2, W3, b3, out, N_NODES);
}

// Round 5
// 155.106 us; speedup vs baseline: 7.8023x; 1.4604x over previous
//
#include <hip/hip_runtime.h>
#include <hip/hip_bf16.h>
#include <cmath>

constexpr int N_NODES = 10000;
constexpr int D_IN = 128;   // GraphConv dim
constexpr int H_DIM = 256;  // MLP hidden

// Bucket sort geometry: bucket = dst>>6 (64 nodes/bucket), 157 buckets.
constexpr int NB = 157;
constexpr int BCAP = 8192;      // avg 4076 edges/bucket, +64 sigma margin
constexpr int EPB_A = 4096;     // edges per phase-A block (256 thr x 16)

typedef unsigned short u16;
typedef short bf16x8 __attribute__((ext_vector_type(8)));  // 8 bf16 = 4 VGPRs
typedef float f32x4 __attribute__((ext_vector_type(4)));

__device__ inline u16 f2bf(float f) {
    return __builtin_bit_cast(u16, __float2bfloat16(f));  // RNE hw cvt
}
__device__ inline float bf2f(u16 u) {
    unsigned int v = (unsigned int)u << 16;
    return __builtin_bit_cast(float, v);
}

// ---------------------------------------------------------------------------
// Phase A: bucket edges by dst>>6. LDS hist + one cursor reservation per
// (block,bucket) -> writes are ~100B contiguous runs (mostly full lines),
// vs R4's 4B random scatter (55B HBM traffic per store).
// packed = (dst & 63) << 16 | src   (src < 65536).
// ---------------------------------------------------------------------------
__global__ __launch_bounds__(256)
void binsort_a(const int* __restrict__ ei, int* __restrict__ gcnt,
               int* __restrict__ buckets, int E) {
    __shared__ int lcnt[NB], gbase[NB];
    const int t = threadIdx.x;
    for (int i = t; i < NB; i += 256) lcnt[i] = 0;
    __syncthreads();
    const int e0 = blockIdx.x * EPB_A + t;
    int packed[16], lpos[16], bb[16];
#pragma unroll
    for (int j = 0; j < 16; ++j) {
        int e = e0 + j * 256;
        if (e < E) {
            int s = ei[e], d = ei[E + e];
            int b = d >> 6;
            bb[j] = b;
            packed[j] = ((d & 63) << 16) | s;
            lpos[j] = atomicAdd(&lcnt[b], 1);
        } else bb[j] = -1;
    }
    __syncthreads();
    for (int i = t; i < NB; i += 256)
        gbase[i] = atomicAdd(&gcnt[i], lcnt[i]);
    __syncthreads();
#pragma unroll
    for (int j = 0; j < 16; ++j)
        if (bb[j] >= 0)
            buckets[bb[j] * BCAP + gbase[bb[j]] + lpos[j]] = packed[j];
}

// ---------------------------------------------------------------------------
// Exclusive scan over the 157 bucket counts -> bucket bases; offsets[N]=E.
// One wave, 3 values/lane.
// ---------------------------------------------------------------------------
__global__ __launch_bounds__(64)
void bucket_scan(const int* __restrict__ gcnt, int* __restrict__ bbase,
                 int* __restrict__ offsets) {
    const int t = threadIdx.x;  // 0..63
    int v[3], sum = 0;
#pragma unroll
    for (int j = 0; j < 3; ++j) {
        int idx = t * 3 + j;
        int d = (idx < NB) ? gcnt[idx] : 0;
        v[j] = sum;
        sum += d;
    }
    int incl = sum;
#pragma unroll
    for (int off = 1; off < 64; off <<= 1) {
        int o = __shfl_up(incl, off);
        if (t >= off) incl += o;
    }
    int excl = incl - sum;
#pragma unroll
    for (int j = 0; j < 3; ++j) {
        int idx = t * 3 + j;
        if (idx < NB) bbase[idx] = excl + v[j];
    }
    if (t == 63) offsets[N_NODES] = incl;  // total = E
}

// ---------------------------------------------------------------------------
// Phase B: one block per bucket. Stage bucket's edges in LDS, per-node hist
// (64 counters) + wave scan -> write this bucket's contiguous ~16KB slice of
// sorted_src from ONE CU (full-line writebacks only). Emits offsets[] too:
// offsets telescope across buckets (base[b]+excl[63]+deg[63] == base[b+1]).
// ---------------------------------------------------------------------------
__global__ __launch_bounds__(256)
void binsort_b(const int* __restrict__ gcnt, const int* __restrict__ bbase,
               const int* __restrict__ buckets, int* __restrict__ sorted_src,
               int* __restrict__ offsets) {
    __shared__ int edges[BCAP];
    __shared__ int deg[64], cur[64];
    const int b = blockIdx.x, t = threadIdx.x;
    int cnt = gcnt[b]; if (cnt > BCAP) cnt = BCAP;
    const int base = bbase[b];
    if (t < 64) deg[t] = 0;
    __syncthreads();
    for (int i = t; i < cnt; i += 256) {
        int p = buckets[b * BCAP + i];
        edges[i] = p;
        atomicAdd(&deg[p >> 16], 1);
    }
    __syncthreads();
    if (t < 64) {
        int d = deg[t];
        int incl = d;
#pragma unroll
        for (int off = 1; off < 64; off <<= 1) {
            int o = __shfl_up(incl, off);
            if (t >= off) incl += o;
        }
        int excl = incl - d;
        cur[t] = excl;
        int node = b * 64 + t;
        if (node < N_NODES) offsets[node] = base + excl;
    }
    __syncthreads();
    for (int i = t; i < cnt; i += 256) {
        int p = edges[i];
        int pos = atomicAdd(&cur[p >> 16], 1);
        sorted_src[base + pos] = p & 0xffff;
    }
}

// ---------------------------------------------------------------------------
// Gather-sum, ILP x4, fp32 accumulate, bf16 output into A0 = [agg_bf | x_bf].
// ---------------------------------------------------------------------------
__global__ __launch_bounds__(256)
void gather_sum_kernel(const float* __restrict__ x,
                       const int* __restrict__ offsets,
                       const int* __restrict__ sorted_src,
                       u16* __restrict__ A0, int M) {
    int wid = (blockIdx.x * blockDim.x + threadIdx.x) >> 6;
    if (wid >= M) return;
    int lane = threadIdx.x & 63;
    int c = (lane & 31) * 4;
    int r = lane >> 5;
    int beg = offsets[wid], end = offsets[wid + 1];
    int half = (end - beg + 1) >> 1;
    int i = r ? beg + half : beg;
    const int i1 = r ? end : beg + half;
    float4 a0 = {0, 0, 0, 0}, a1 = {0, 0, 0, 0}, a2 = {0, 0, 0, 0}, a3 = {0, 0, 0, 0};
    for (; i + 4 <= i1; i += 4) {
        int s0 = sorted_src[i + 0], s1 = sorted_src[i + 1];
        int s2 = sorted_src[i + 2], s3 = sorted_src[i + 3];
        const float4 v0 = *reinterpret_cast<const float4*>(x + (size_t)s0 * D_IN + c);
        const float4 v1 = *reinterpret_cast<const float4*>(x + (size_t)s1 * D_IN + c);
        const float4 v2 = *reinterpret_cast<const float4*>(x + (size_t)s2 * D_IN + c);
        const float4 v3 = *reinterpret_cast<const float4*>(x + (size_t)s3 * D_IN + c);
        a0.x += v0.x; a0.y += v0.y; a0.z += v0.z; a0.w += v0.w;
        a1.x += v1.x; a1.y += v1.y; a1.z += v1.z; a1.w += v1.w;
        a2.x += v2.x; a2.y += v2.y; a2.z += v2.z; a2.w += v2.w;
        a3.x += v3.x; a3.y += v3.y; a3.z += v3.z; a3.w += v3.w;
    }
    for (; i < i1; ++i) {
        int s = sorted_src[i];
        const float4 v = *reinterpret_cast<const float4*>(x + (size_t)s * D_IN + c);
        a0.x += v.x; a0.y += v.y; a0.z += v.z; a0.w += v.w;
    }
    a0.x += a1.x + a2.x + a3.x;
    a0.y += a1.y + a2.y + a3.y;
    a0.z += a1.z + a2.z + a3.z;
    a0.w += a1.w + a2.w + a3.w;
    a0.x += __shfl_xor(a0.x, 32);
    a0.y += __shfl_xor(a0.y, 32);
    a0.z += __shfl_xor(a0.z, 32);
    a0.w += __shfl_xor(a0.w, 32);
    if (r == 0) {
        ushort4 o;
        o.x = f2bf(a0.x); o.y = f2bf(a0.y); o.z = f2bf(a0.z); o.w = f2bf(a0.w);
        *reinterpret_cast<ushort4*>(A0 + (size_t)wid * 256 + c) = o;
    }
}

// ---------------------------------------------------------------------------
// Cast x (fp32 [10000,128]) into A0 rows' second half (bf16, stride 256).
// ---------------------------------------------------------------------------
__global__ __launch_bounds__(256)
void cast_x_kernel(const float* __restrict__ x, u16* __restrict__ A0, int total4) {
    int idx = blockIdx.x * blockDim.x + threadIdx.x;
    if (idx >= total4) return;
    int row = idx >> 5;
    int c = (idx & 31) * 4;
    float4 v = *reinterpret_cast<const float4*>(x + (size_t)row * D_IN + c);
    ushort4 o;
    o.x = f2bf(v.x); o.y = f2bf(v.y); o.z = f2bf(v.z); o.w = f2bf(v.w);
    *reinterpret_cast<ushort4*>(A0 + (size_t)row * 256 + 128 + c) = o;
}

// ---------------------------------------------------------------------------
// Cast weights to bf16: Wcat[128][256] = [W_rel | W_root], W1b, W2b.
// ---------------------------------------------------------------------------
__global__ __launch_bounds__(256)
void cast_w_kernel(const float* __restrict__ W_rel, const float* __restrict__ W_root,
                   const float* __restrict__ W1, const float* __restrict__ W2,
                   u16* __restrict__ Wcat, u16* __restrict__ W1b, u16* __restrict__ W2b) {
    int idx4 = (blockIdx.x * blockDim.x + threadIdx.x) * 4;
    const float* src;
    u16* dst;
    if (idx4 < 32768) {            // Wcat
        int n = idx4 >> 8, k = idx4 & 255;
        src = (k < 128) ? W_rel + n * 128 + k : W_root + n * 128 + (k - 128);
        dst = Wcat + idx4;
    } else if (idx4 < 65536) {     // W1
        src = W1 + (idx4 - 32768);
        dst = W1b + (idx4 - 32768);
    } else {                       // W2
        src = W2 + (idx4 - 65536);
        dst = W2b + (idx4 - 65536);
    }
    float4 v = *reinterpret_cast<const float4*>(src);
    ushort4 o;
    o.x = f2bf(v.x); o.y = f2bf(v.y); o.z = f2bf(v.z); o.w = f2bf(v.w);
    *reinterpret_cast<ushort4*>(dst) = o;
}

// ---------------------------------------------------------------------------
// bf16 MFMA GEMM: C[M,N] = act(A@W^T + bias), fp32 acc, bf16 C.
// Block 256 thr = 4 waves (2x2 of 32x32), tile 64x64, BK=64 LDS-staged.
// Frag layouts (m89/m91-verified): A[m=lane&15][k=quad*8+j],
// B[n=lane&15][k=quad*8+j], C/D col=lane&15 row=quad*4+reg.
// ---------------------------------------------------------------------------
template <int ACT>  // 0 = none, 1 = relu
__global__ __launch_bounds__(256)
void mfma_gemm(const u16* __restrict__ A, const u16* __restrict__ W,
               const float* __restrict__ bias, u16* __restrict__ C,
               int M, int N, int K) {
    constexpr int LDT = 80;
    __shared__ short As[64 * LDT];
    __shared__ short Ws[64 * LDT];
    const int t = threadIdx.x;
    const int m0 = blockIdx.y * 64;
    const int n0 = blockIdx.x * 64;
    const int w = t >> 6, lane = t & 63;
    const int wr = w >> 1, wc = w & 1;
    const int m_lane = lane & 15, q = lane >> 4;
    f32x4 acc[2][2] = {};
    for (int k0 = 0; k0 < K; k0 += 64) {
        __syncthreads();
#pragma unroll
        for (int L = 0; L < 2; ++L) {
            int idx = t + 256 * L;
            int row = idx >> 3;
            int kc = (idx & 7) * 8;
            int ar = m0 + row; if (ar >= M) ar = M - 1;   // stores guarded
            bf16x8 av = *reinterpret_cast<const bf16x8*>(A + (size_t)ar * K + k0 + kc);
            bf16x8 wv = *reinterpret_cast<const bf16x8*>(W + (size_t)(n0 + row) * K + k0 + kc);
            *reinterpret_cast<bf16x8*>(&As[row * LDT + kc]) = av;
            *reinterpret_cast<bf16x8*>(&Ws[row * LDT + kc]) = wv;
        }
        __syncthreads();
#pragma unroll
        for (int kk = 0; kk < 64; kk += 32) {
            const int koff = kk + q * 8;
            bf16x8 af[2], bf[2];
#pragma unroll
            for (int i = 0; i < 2; ++i)
                af[i] = *reinterpret_cast<const bf16x8*>(
                    &As[(wr * 32 + i * 16 + m_lane) * LDT + koff]);
#pragma unroll
            for (int j = 0; j < 2; ++j)
                bf[j] = *reinterpret_cast<const bf16x8*>(
                    &Ws[(wc * 32 + j * 16 + m_lane) * LDT + koff]);
#pragma unroll
            for (int i = 0; i < 2; ++i)
#pragma unroll
                for (int j = 0; j < 2; ++j)
                    acc[i][j] = __builtin_amdgcn_mfma_f32_16x16x32_bf16(
                        af[i], bf[j], acc[i][j], 0, 0, 0);
        }
    }
#pragma unroll
    for (int i = 0; i < 2; ++i)
#pragma unroll
        for (int j = 0; j < 2; ++j) {
            int col = n0 + wc * 32 + j * 16 + m_lane;
            float b = bias[col];
#pragma unroll
            for (int r = 0; r < 4; ++r) {
                int row = m0 + wr * 32 + i * 16 + q * 4 + r;
                if (row >= M) continue;
                float v = acc[i][j][r] + b;
                if (ACT == 1) v = fmaxf(v, 0.f);
                C[(size_t)row * N + col] = f2bf(v);
            }
        }
}

// ---------------------------------------------------------------------------
// Head: out[n] = sigmoid( dot(h2_bf16[n], W3) + b3 ). One wave per node.
// ---------------------------------------------------------------------------
__global__ __launch_bounds__(256)
void head_kernel(const u16* __restrict__ h2, const float* __restrict__ W3,
                 const float* __restrict__ b3, float* __restrict__ out, int M) {
    int wave = threadIdx.x >> 6;
    int lane = threadIdx.x & 63;
    int n = blockIdx.x * 4 + wave;
    if (n >= M) return;
    ushort4 hu = *reinterpret_cast<const ushort4*>(h2 + (size_t)n * H_DIM + lane * 4);
    float4 w = *reinterpret_cast<const float4*>(W3 + lane * 4);
    float dot = bf2f(hu.x) * w.x + bf2f(hu.y) * w.y + bf2f(hu.z) * w.z + bf2f(hu.w) * w.w;
#pragma unroll
    for (int off = 32; off > 0; off >>= 1) dot += __shfl_down(dot, off);
    if (lane == 0) {
        float v = dot + b3[0];
        out[n] = 1.0f / (1.0f + expf(-v));
    }
}

extern "C" void kernel_launch(void* const* d_in, const int* in_sizes, int n_in,
                              void* d_out, int out_size, void* d_ws, size_t ws_size,
                              hipStream_t stream) {
    const float* x      = (const float*)d_in[0];
    const int*   ei     = (const int*)d_in[1];   // [2, E]: src row then dst row
    const float* W_rel  = (const float*)d_in[2];
    const float* b_rel  = (const float*)d_in[3];
    const float* W_root = (const float*)d_in[4];
    const float* W1     = (const float*)d_in[5];
    const float* b1     = (const float*)d_in[6];
    const float* W2     = (const float*)d_in[7];
    const float* b2     = (const float*)d_in[8];
    const float* W3     = (const float*)d_in[9];
    const float* b3     = (const float*)d_in[10];
    float* out = (float*)d_out;
    const int E = in_sizes[1] / 2;

    char* p = (char*)d_ws;
    auto carve = [&](size_t bytes) { char* r = p; p += (bytes + 63) & ~size_t(63); return r; };
    u16* A0   = (u16*)carve((size_t)N_NODES * 256 * 2);  // [agg_bf | x_bf]
    u16* h0   = (u16*)carve((size_t)N_NODES * 128 * 2);
    u16* h1   = (u16*)carve((size_t)N_NODES * 256 * 2);
    u16* h2   = (u16*)carve((size_t)N_NODES * 256 * 2);
    u16* Wcat = (u16*)carve(128 * 256 * 2);
    u16* W1b  = (u16*)carve(256 * 128 * 2);
    u16* W2b  = (u16*)carve(256 * 256 * 2);
    int* offsets    = (int*)carve((N_NODES + 4) * 4);
    int* gcnt       = (int*)carve(NB * 4);
    int* bbase      = (int*)carve(NB * 4);
    int* buckets    = (int*)carve((size_t)NB * BCAP * 4);   // 5.1 MB
    int* sorted_src = (int*)carve((size_t)E * 4);

    hipMemsetAsync(gcnt, 0, NB * sizeof(int), stream);
    binsort_a<<<(E + EPB_A - 1) / EPB_A, 256, 0, stream>>>(ei, gcnt, buckets, E);
    bucket_scan<<<1, 64, 0, stream>>>(gcnt, bbase, offsets);
    binsort_b<<<NB, 256, 0, stream>>>(gcnt, bbase, buckets, sorted_src, offsets);
    gather_sum_kernel<<<(N_NODES * 64 + 255) / 256, 256, 0, stream>>>(
        x, offsets, sorted_src, A0, N_NODES);
    cast_x_kernel<<<(N_NODES * 32 + 255) / 256, 256, 0, stream>>>(x, A0, N_NODES * 32);
    cast_w_kernel<<<131072 / 4 / 256, 256, 0, stream>>>(W_rel, W_root, W1, W2,
                                                        Wcat, W1b, W2b);
    {   // GraphConv: h0 = A0 @ Wcat^T + b_rel   (K=256, N=128)
        dim3 g(128 / 64, (N_NODES + 63) / 64);
        mfma_gemm<0><<<g, 256, 0, stream>>>(A0, Wcat, b_rel, h0, N_NODES, 128, 256);
    }
    {   // h1 = relu(h0 @ W1^T + b1)   (K=128, N=256)
        dim3 g(256 / 64, (N_NODES + 63) / 64);
        mfma_gemm<1><<<g, 256, 0, stream>>>(h0, W1b, b1, h1, N_NODES, 256, 128);
    }
    {   // h2 = relu(h1 @ W2^T + b2)   (K=256, N=256)
        dim3 g(256 / 64, (N_NODES + 63) / 64);
        mfma_gemm<1><<<g, 256, 0, stream>>>(h1, W2b, b2, h2, N_NODES, 256, 256);
    }
    head_kernel<<<(N_NODES + 3) / 4, 256, 0, stream>>>(h2, W3, b3, out, N_NODES);
}

// Round 6
// 152.780 us; speedup vs baseline: 7.9211x; 1.0152x over previous
//
#include <hip/hip_runtime.h>
#include <hip/hip_bf16.h>
#include <cmath>

constexpr int N_NODES = 10000;
constexpr int D_IN = 128;   // GraphConv dim
constexpr int H_DIM = 256;  // MLP hidden

// Bucket sort geometry: bucket = dst>>6 (64 nodes/bucket), 157 buckets.
constexpr int NB = 157;
constexpr int BCAP = 8192;      // avg 4076 edges/bucket; 6-sigma max ~4500
constexpr int EPB_A = 4096;     // edges per phase-A block (256 thr x 16)

typedef unsigned short u16;
typedef short bf16x8 __attribute__((ext_vector_type(8)));  // 8 bf16 = 4 VGPRs
typedef float f32x4 __attribute__((ext_vector_type(4)));

__device__ inline u16 f2bf(float f) {
    return __builtin_bit_cast(u16, __float2bfloat16(f));  // RNE hw cvt
}
__device__ inline float bf2f(u16 u) {
    unsigned int v = (unsigned int)u << 16;
    return __builtin_bit_cast(float, v);
}

// ---------------------------------------------------------------------------
// Prep (one kernel, 3 jobs by blockIdx):
//  blocks [0,1250):   cast x fp32 -> dense x_bf [10000,128] AND A0 rows'
//                     second half (stride 256, offset 128)
//  blocks [1250,1378): cast weights -> Wcat[128][256]=[W_rel|W_root],
//                     W1b[256][128], W2b[256][256]
//  block 1378:        zero gcnt[157]
// ---------------------------------------------------------------------------
constexpr int PREP_XB = 1250, PREP_WB = 128;
__global__ __launch_bounds__(256)
void prep_kernel(const float* __restrict__ x,
                 const float* __restrict__ W_rel, const float* __restrict__ W_root,
                 const float* __restrict__ W1, const float* __restrict__ W2,
                 u16* __restrict__ x_bf, u16* __restrict__ A0,
                 u16* __restrict__ Wcat, u16* __restrict__ W1b, u16* __restrict__ W2b,
                 int* __restrict__ gcnt) {
    const int bid = blockIdx.x, t = threadIdx.x;
    if (bid < PREP_XB) {
        int idx = bid * 256 + t;                 // float4 chunk id
        if (idx >= N_NODES * 32) return;
        int row = idx >> 5, c = (idx & 31) * 4;
        float4 v = *reinterpret_cast<const float4*>(x + (size_t)row * D_IN + c);
        ushort4 o;
        o.x = f2bf(v.x); o.y = f2bf(v.y); o.z = f2bf(v.z); o.w = f2bf(v.w);
        *reinterpret_cast<ushort4*>(x_bf + (size_t)row * D_IN + c) = o;
        *reinterpret_cast<ushort4*>(A0 + (size_t)row * 256 + 128 + c) = o;
    } else if (bid < PREP_XB + PREP_WB) {
        int idx4 = ((bid - PREP_XB) * 256 + t) * 4;   // 131072 weight elems
        const float* src;
        u16* dst;
        if (idx4 < 32768) {            // Wcat
            int n = idx4 >> 8, k = idx4 & 255;
            src = (k < 128) ? W_rel + n * 128 + k : W_root + n * 128 + (k - 128);
            dst = Wcat + idx4;
        } else if (idx4 < 65536) {     // W1
            src = W1 + (idx4 - 32768);
            dst = W1b + (idx4 - 32768);
        } else {                       // W2
            src = W2 + (idx4 - 65536);
            dst = W2b + (idx4 - 65536);
        }
        float4 v = *reinterpret_cast<const float4*>(src);
        ushort4 o;
        o.x = f2bf(v.x); o.y = f2bf(v.y); o.z = f2bf(v.z); o.w = f2bf(v.w);
        *reinterpret_cast<ushort4*>(dst) = o;
    } else {
        if (t < NB) gcnt[t] = 0;
    }
}

// ---------------------------------------------------------------------------
// Phase A: bucket edges by dst>>6. LDS hist + one cursor reservation per
// (block,bucket) -> ~100B contiguous write runs (mostly full lines).
// packed = (dst & 63) << 16 | src   (src < 65536).
// ---------------------------------------------------------------------------
__global__ __launch_bounds__(256)
void binsort_a(const int* __restrict__ ei, int* __restrict__ gcnt,
               int* __restrict__ buckets, int E) {
    __shared__ int lcnt[NB], gbase[NB];
    const int t = threadIdx.x;
    for (int i = t; i < NB; i += 256) lcnt[i] = 0;
    __syncthreads();
    const int e0 = blockIdx.x * EPB_A + t;
    int packed[16], lpos[16], bb[16];
#pragma unroll
    for (int j = 0; j < 16; ++j) {
        int e = e0 + j * 256;
        if (e < E) {
            int s = ei[e], d = ei[E + e];
            int b = d >> 6;
            bb[j] = b;
            packed[j] = ((d & 63) << 16) | s;
            lpos[j] = atomicAdd(&lcnt[b], 1);
        } else bb[j] = -1;
    }
    __syncthreads();
    for (int i = t; i < NB; i += 256)
        gbase[i] = atomicAdd(&gcnt[i], lcnt[i]);
    __syncthreads();
#pragma unroll
    for (int j = 0; j < 16; ++j)
        if (bb[j] >= 0)
            buckets[bb[j] * BCAP + gbase[bb[j]] + lpos[j]] = packed[j];
}

// ---------------------------------------------------------------------------
// Phase B: one block per bucket. Inline redundant 157-scan of gcnt gives this
// bucket's base (saves the bucket_scan dispatch). Stage edges in LDS, 64-way
// per-node hist + wave scan -> contiguous single-CU writes of sorted_src,
// emits offsets[] (telescopes across buckets). offsets[N]=E by block 0.
// ---------------------------------------------------------------------------
__global__ __launch_bounds__(256)
void binsort_b(const int* __restrict__ gcnt, const int* __restrict__ buckets,
               int* __restrict__ sorted_src, int* __restrict__ offsets, int E) {
    __shared__ int edges[BCAP];
    __shared__ int deg[64], cur[64];
    __shared__ int sbase;
    const int b = blockIdx.x, t = threadIdx.x;
    if (t < 64) {  // wave 0: exclusive scan of gcnt[0..NB) to find base[b]
        int v[3], sum = 0;
#pragma unroll
        for (int j = 0; j < 3; ++j) {
            int idx = t * 3 + j;
            int d = (idx < NB) ? gcnt[idx] : 0;
            v[j] = sum;
            sum += d;
        }
        int incl = sum;
#pragma unroll
        for (int off = 1; off < 64; off <<= 1) {
            int o = __shfl_up(incl, off);
            if (t >= off) incl += o;
        }
        int excl = incl - sum;
#pragma unroll
        for (int j = 0; j < 3; ++j)
            if (t * 3 + j == b) sbase = excl + v[j];
    }
    if (t < 64) deg[t] = 0;
    if (b == 0 && t == 0) offsets[N_NODES] = E;
    __syncthreads();
    const int base = sbase;
    int cnt = gcnt[b]; if (cnt > BCAP) cnt = BCAP;
    for (int i = t; i < cnt; i += 256) {
        int p = buckets[b * BCAP + i];
        edges[i] = p;
        atomicAdd(&deg[p >> 16], 1);
    }
    __syncthreads();
    if (t < 64) {
        int d = deg[t];
        int incl = d;
#pragma unroll
        for (int off = 1; off < 64; off <<= 1) {
            int o = __shfl_up(incl, off);
            if (t >= off) incl += o;
        }
        int excl = incl - d;
        cur[t] = excl;
        int node = b * 64 + t;
        if (node < N_NODES) offsets[node] = base + excl;
    }
    __syncthreads();
    for (int i = t; i < cnt; i += 256) {
        int p = edges[i];
        int pos = atomicAdd(&cur[p >> 16], 1);
        sorted_src[base + pos] = p & 0xffff;
    }
}

// ---------------------------------------------------------------------------
// Gather-sum over bf16 x (2.56 MB -> single-XCD-L2 resident; half the read
// bytes of R5's fp32 gather). ILP x4, fp32 accumulate, bf16 out into A0
// first half. One wave/node; half-wave r takes a contiguous half-range.
// ---------------------------------------------------------------------------
__global__ __launch_bounds__(256)
void gather_sum_kernel(const u16* __restrict__ x_bf,
                       const int* __restrict__ offsets,
                       const int* __restrict__ sorted_src,
                       u16* __restrict__ A0, int M) {
    int wid = (blockIdx.x * blockDim.x + threadIdx.x) >> 6;
    if (wid >= M) return;
    int lane = threadIdx.x & 63;
    int c = (lane & 31) * 4;
    int r = lane >> 5;
    int beg = offsets[wid], end = offsets[wid + 1];
    int half = (end - beg + 1) >> 1;
    int i = r ? beg + half : beg;
    const int i1 = r ? end : beg + half;
    float4 a0 = {0, 0, 0, 0}, a1 = {0, 0, 0, 0}, a2 = {0, 0, 0, 0}, a3 = {0, 0, 0, 0};
    for (; i + 4 <= i1; i += 4) {
        int s0 = sorted_src[i + 0], s1 = sorted_src[i + 1];
        int s2 = sorted_src[i + 2], s3 = sorted_src[i + 3];
        ushort4 v0 = *reinterpret_cast<const ushort4*>(x_bf + (size_t)s0 * D_IN + c);
        ushort4 v1 = *reinterpret_cast<const ushort4*>(x_bf + (size_t)s1 * D_IN + c);
        ushort4 v2 = *reinterpret_cast<const ushort4*>(x_bf + (size_t)s2 * D_IN + c);
        ushort4 v3 = *reinterpret_cast<const ushort4*>(x_bf + (size_t)s3 * D_IN + c);
        a0.x += bf2f(v0.x); a0.y += bf2f(v0.y); a0.z += bf2f(v0.z); a0.w += bf2f(v0.w);
        a1.x += bf2f(v1.x); a1.y += bf2f(v1.y); a1.z += bf2f(v1.z); a1.w += bf2f(v1.w);
        a2.x += bf2f(v2.x); a2.y += bf2f(v2.y); a2.z += bf2f(v2.z); a2.w += bf2f(v2.w);
        a3.x += bf2f(v3.x); a3.y += bf2f(v3.y); a3.z += bf2f(v3.z); a3.w += bf2f(v3.w);
    }
    for (; i < i1; ++i) {
        int s = sorted_src[i];
        ushort4 v = *reinterpret_cast<const ushort4*>(x_bf + (size_t)s * D_IN + c);
        a0.x += bf2f(v.x); a0.y += bf2f(v.y); a0.z += bf2f(v.z); a0.w += bf2f(v.w);
    }
    a0.x += a1.x + a2.x + a3.x;
    a0.y += a1.y + a2.y + a3.y;
    a0.z += a1.z + a2.z + a3.z;
    a0.w += a1.w + a2.w + a3.w;
    a0.x += __shfl_xor(a0.x, 32);
    a0.y += __shfl_xor(a0.y, 32);
    a0.z += __shfl_xor(a0.z, 32);
    a0.w += __shfl_xor(a0.w, 32);
    if (r == 0) {
        ushort4 o;
        o.x = f2bf(a0.x); o.y = f2bf(a0.y); o.z = f2bf(a0.z); o.w = f2bf(a0.w);
        *reinterpret_cast<ushort4*>(A0 + (size_t)wid * 256 + c) = o;
    }
}

// ---------------------------------------------------------------------------
// Fused MLP: per block, 64 rows end-to-end:
//   h0 = A0rows @ Wcat^T + b_rel            (64x128, K=256)
//   h1 = relu(h0 @ W1^T + b1)               (64x256, K=128)
//   h2 = relu(h1 @ W2^T + b2)               (64x256, K=256)
//   out = sigmoid(h2 @ W3 + b3)             (64x1, fused reduction)
// A-side + intermediates in LDS (51.7 KB); weight B-fragments read straight
// from global (260 KB total, L2-hot; ~60 MB aggregate L2 traffic).
// Frag layouts as validated in R4/R5: A/B [row=lane&15][k=q*8+j],
// C/D col=lane&15 row=q*4+reg. 4 waves = 2(m) x 2(n).
// LDS strides 264/136 u16 (=132/68 dwords, ==4 mod 32 -> 2-way, free).
// ---------------------------------------------------------------------------
__global__ __launch_bounds__(256)
void fused_mlp(const u16* __restrict__ A0, const u16* __restrict__ Wcat,
               const u16* __restrict__ W1b, const u16* __restrict__ W2b,
               const float* __restrict__ b_rel, const float* __restrict__ b1,
               const float* __restrict__ b2, const float* __restrict__ W3,
               const float* __restrict__ b3, float* __restrict__ out, int M) {
    __shared__ u16 sm[25600];        // [0,16896): A_in then h1 (stride 264)
                                     // [16896,25600): h0 (stride 136)
    __shared__ float part[64][2];
    u16* bufA  = sm;
    u16* bufH0 = sm + 16896;
    const int t = threadIdx.x, b = blockIdx.x;
    const int w = t >> 6, lane = t & 63;
    const int wm = w >> 1, wn = w & 1;
    const int l16 = lane & 15, q = lane >> 4;
    const int r0 = b * 64;

    // Stage this block's 64 A0 rows (bf16 [64][256]) into LDS.
    for (int idx = t; idx < 2048; idx += 256) {
        int row = idx >> 5, kc = (idx & 31) * 8;
        int gr = r0 + row; if (gr >= M) gr = M - 1;
        bf16x8 v = *reinterpret_cast<const bf16x8*>(A0 + (size_t)gr * 256 + kc);
        *reinterpret_cast<bf16x8*>(bufA + row * 264 + kc) = v;
    }
    __syncthreads();

    // Phase 1: h0[64][128] = A_in @ Wcat^T + b_rel   (no activation)
    {
        f32x4 acc[2][4] = {};
#pragma unroll
        for (int k0 = 0; k0 < 256; k0 += 32) {
            bf16x8 af[2];
#pragma unroll
            for (int i = 0; i < 2; ++i)
                af[i] = *reinterpret_cast<const bf16x8*>(
                    bufA + (wm * 32 + i * 16 + l16) * 264 + k0 + q * 8);
#pragma unroll
            for (int jj = 0; jj < 4; ++jj) {
                int col = wn * 64 + jj * 16 + l16;
                bf16x8 bfv = *reinterpret_cast<const bf16x8*>(
                    Wcat + (size_t)col * 256 + k0 + q * 8);
                acc[0][jj] = __builtin_amdgcn_mfma_f32_16x16x32_bf16(af[0], bfv, acc[0][jj], 0, 0, 0);
                acc[1][jj] = __builtin_amdgcn_mfma_f32_16x16x32_bf16(af[1], bfv, acc[1][jj], 0, 0, 0);
            }
        }
#pragma unroll
        for (int i = 0; i < 2; ++i)
#pragma unroll
            for (int jj = 0; jj < 4; ++jj) {
                int col = wn * 64 + jj * 16 + l16;
                float bb = b_rel[col];
#pragma unroll
                for (int r = 0; r < 4; ++r) {
                    int row = wm * 32 + i * 16 + q * 4 + r;
                    bufH0[row * 136 + col] = f2bf(acc[i][jj][r] + bb);
                }
            }
    }
    __syncthreads();

    // Phase 2: h1[64][256] = relu(h0 @ W1^T + b1); h1 overlays A_in (dead).
    {
        f32x4 acc[2][8] = {};
#pragma unroll
        for (int k0 = 0; k0 < 128; k0 += 32) {
            bf16x8 af[2];
#pragma unroll
            for (int i = 0; i < 2; ++i)
                af[i] = *reinterpret_cast<const bf16x8*>(
                    bufH0 + (wm * 32 + i * 16 + l16) * 136 + k0 + q * 8);
#pragma unroll
            for (int jj = 0; jj < 8; ++jj) {
                int col = wn * 128 + jj * 16 + l16;
                bf16x8 bfv = *reinterpret_cast<const bf16x8*>(
                    W1b + (size_t)col * 128 + k0 + q * 8);
                acc[0][jj] = __builtin_amdgcn_mfma_f32_16x16x32_bf16(af[0], bfv, acc[0][jj], 0, 0, 0);
                acc[1][jj] = __builtin_amdgcn_mfma_f32_16x16x32_bf16(af[1], bfv, acc[1][jj], 0, 0, 0);
            }
        }
#pragma unroll
        for (int i = 0; i < 2; ++i)
#pragma unroll
            for (int jj = 0; jj < 8; ++jj) {
                int col = wn * 128 + jj * 16 + l16;
                float bb = b1[col];
#pragma unroll
                for (int r = 0; r < 4; ++r) {
                    int row = wm * 32 + i * 16 + q * 4 + r;
                    bufA[row * 264 + col] = f2bf(fmaxf(acc[i][jj][r] + bb, 0.f));
                }
            }
    }
    __syncthreads();

    // Phase 3 + head: h2 = relu(h1 @ W2^T + b2); out = sigmoid(h2 @ W3 + b3)
    {
        f32x4 acc[2][8] = {};
#pragma unroll
        for (int k0 = 0; k0 < 256; k0 += 32) {
            bf16x8 af[2];
#pragma unroll
            for (int i = 0; i < 2; ++i)
                af[i] = *reinterpret_cast<const bf16x8*>(
                    bufA + (wm * 32 + i * 16 + l16) * 264 + k0 + q * 8);
#pragma unroll
            for (int jj = 0; jj < 8; ++jj) {
                int col = wn * 128 + jj * 16 + l16;
                bf16x8 bfv = *reinterpret_cast<const bf16x8*>(
                    W2b + (size_t)col * 256 + k0 + q * 8);
                acc[0][jj] = __builtin_amdgcn_mfma_f32_16x16x32_bf16(af[0], bfv, acc[0][jj], 0, 0, 0);
                acc[1][jj] = __builtin_amdgcn_mfma_f32_16x16x32_bf16(af[1], bfv, acc[1][jj], 0, 0, 0);
            }
        }
        // Weighted column reduction: s[i][r] = sum_col relu(h2)*W3[col]
        float s[2][4] = {};
#pragma unroll
        for (int jj = 0; jj < 8; ++jj) {
            int col = wn * 128 + jj * 16 + l16;
            float bb = b2[col], ww = W3[col];
#pragma unroll
            for (int i = 0; i < 2; ++i)
#pragma unroll
                for (int r = 0; r < 4; ++r)
                    s[i][r] = fmaf(fmaxf(acc[i][jj][r] + bb, 0.f), ww, s[i][r]);
        }
#pragma unroll
        for (int off = 1; off < 16; off <<= 1)
#pragma unroll
            for (int i = 0; i < 2; ++i)
#pragma unroll
                for (int r = 0; r < 4; ++r)
                    s[i][r] += __shfl_xor(s[i][r], off);
        if (l16 == 0)
#pragma unroll
            for (int i = 0; i < 2; ++i)
#pragma unroll
                for (int r = 0; r < 4; ++r)
                    part[wm * 32 + i * 16 + q * 4 + r][wn] = s[i][r];
    }
    __syncthreads();
    if (t < 64) {
        int node = r0 + t;
        if (node < M) {
            float v = part[t][0] + part[t][1] + b3[0];
            out[node] = 1.0f / (1.0f + expf(-v));
        }
    }
}

extern "C" void kernel_launch(void* const* d_in, const int* in_sizes, int n_in,
                              void* d_out, int out_size, void* d_ws, size_t ws_size,
                              hipStream_t stream) {
    const float* x      = (const float*)d_in[0];
    const int*   ei     = (const int*)d_in[1];   // [2, E]: src row then dst row
    const float* W_rel  = (const float*)d_in[2];
    const float* b_rel  = (const float*)d_in[3];
    const float* W_root = (const float*)d_in[4];
    const float* W1     = (const float*)d_in[5];
    const float* b1     = (const float*)d_in[6];
    const float* W2     = (const float*)d_in[7];
    const float* b2     = (const float*)d_in[8];
    const float* W3     = (const float*)d_in[9];
    const float* b3     = (const float*)d_in[10];
    float* out = (float*)d_out;
    const int E = in_sizes[1] / 2;

    char* p = (char*)d_ws;
    auto carve = [&](size_t bytes) { char* r = p; p += (bytes + 63) & ~size_t(63); return r; };
    u16* A0   = (u16*)carve((size_t)N_NODES * 256 * 2);  // [agg_bf | x_bf] rows
    u16* x_bf = (u16*)carve((size_t)N_NODES * D_IN * 2); // dense bf16 x
    u16* Wcat = (u16*)carve(128 * 256 * 2);
    u16* W1b  = (u16*)carve(256 * 128 * 2);
    u16* W2b  = (u16*)carve(256 * 256 * 2);
    int* offsets    = (int*)carve((N_NODES + 4) * 4);
    int* gcnt       = (int*)carve(NB * 4);
    int* buckets    = (int*)carve((size_t)NB * BCAP * 4);   // 5.1 MB
    int* sorted_src = (int*)carve((size_t)E * 4);

    prep_kernel<<<PREP_XB + PREP_WB + 1, 256, 0, stream>>>(
        x, W_rel, W_root, W1, W2, x_bf, A0, Wcat, W1b, W2b, gcnt);
    binsort_a<<<(E + EPB_A - 1) / EPB_A, 256, 0, stream>>>(ei, gcnt, buckets, E);
    binsort_b<<<NB, 256, 0, stream>>>(gcnt, buckets, sorted_src, offsets, E);
    gather_sum_kernel<<<(N_NODES * 64 + 255) / 256, 256, 0, stream>>>(
        x_bf, offsets, sorted_src, A0, N_NODES);
    fused_mlp<<<(N_NODES + 63) / 64, 256, 0, stream>>>(
        A0, Wcat, W1b, W2b, b_rel, b1, b2, W3, b3, out, N_NODES);
}

// Round 7
// 140.503 us; speedup vs baseline: 8.6132x; 1.0874x over previous
//
#include <hip/hip_runtime.h>
#include <hip/hip_bf16.h>
#include <cmath>

constexpr int N_NODES = 10000;
constexpr int D_IN = 128;   // GraphConv dim
constexpr int H_DIM = 256;  // MLP hidden

// Bucket geometry: bucket = dst>>6 (64 nodes/bucket), 157 buckets.
constexpr int NB = 157;
constexpr int BCAP = 8192;      // avg 4076 edges/bucket; 6-sigma max ~4500
constexpr int EPB_A = 4096;     // edges per phase-A block (256 thr x 16)

typedef unsigned short u16;
typedef short bf16x8 __attribute__((ext_vector_type(8)));  // 8 bf16 = 4 VGPRs
typedef float f32x4 __attribute__((ext_vector_type(4)));

__device__ inline u16 f2bf(float f) {
    return __builtin_bit_cast(u16, __float2bfloat16(f));  // RNE hw cvt
}
__device__ inline float bf2f(u16 u) {
    unsigned int v = (unsigned int)u << 16;
    return __builtin_bit_cast(float, v);
}

// ---------------------------------------------------------------------------
// Prep (one kernel, 3 jobs by blockIdx):
//  blocks [0,1250):    cast x fp32 -> dense x_bf [10000,128]
//  blocks [1250,1378): cast weights -> Wcat[128][256]=[W_rel|W_root],
//                      W1b[256][128], W2b[256][256]
//  block 1378:         zero gcnt[157]
// ---------------------------------------------------------------------------
constexpr int PREP_XB = 1250, PREP_WB = 128;
__global__ __launch_bounds__(256)
void prep_kernel(const float* __restrict__ x,
                 const float* __restrict__ W_rel, const float* __restrict__ W_root,
                 const float* __restrict__ W1, const float* __restrict__ W2,
                 u16* __restrict__ x_bf,
                 u16* __restrict__ Wcat, u16* __restrict__ W1b, u16* __restrict__ W2b,
                 int* __restrict__ gcnt) {
    const int bid = blockIdx.x, t = threadIdx.x;
    if (bid < PREP_XB) {
        int idx = bid * 256 + t;                 // float4 chunk id
        if (idx >= N_NODES * 32) return;
        int row = idx >> 5, c = (idx & 31) * 4;
        float4 v = *reinterpret_cast<const float4*>(x + (size_t)row * D_IN + c);
        ushort4 o;
        o.x = f2bf(v.x); o.y = f2bf(v.y); o.z = f2bf(v.z); o.w = f2bf(v.w);
        *reinterpret_cast<ushort4*>(x_bf + (size_t)row * D_IN + c) = o;
    } else if (bid < PREP_XB + PREP_WB) {
        int idx4 = ((bid - PREP_XB) * 256 + t) * 4;   // 131072 weight elems
        const float* src;
        u16* dst;
        if (idx4 < 32768) {            // Wcat
            int n = idx4 >> 8, k = idx4 & 255;
            src = (k < 128) ? W_rel + n * 128 + k : W_root + n * 128 + (k - 128);
            dst = Wcat + idx4;
        } else if (idx4 < 65536) {     // W1
            src = W1 + (idx4 - 32768);
            dst = W1b + (idx4 - 32768);
        } else {                       // W2
            src = W2 + (idx4 - 65536);
            dst = W2b + (idx4 - 65536);
        }
        float4 v = *reinterpret_cast<const float4*>(src);
        ushort4 o;
        o.x = f2bf(v.x); o.y = f2bf(v.y); o.z = f2bf(v.z); o.w = f2bf(v.w);
        *reinterpret_cast<ushort4*>(dst) = o;
    } else {
        if (t < NB) gcnt[t] = 0;
    }
}

// ---------------------------------------------------------------------------
// Phase A: bucket edges by dst>>6. LDS hist + one cursor reservation per
// (block,bucket) -> ~100B contiguous write runs (mostly full lines).
// packed = (dst & 63) << 16 | src   (src < 65536).
// ---------------------------------------------------------------------------
__global__ __launch_bounds__(256)
void binsort_a(const int* __restrict__ ei, int* __restrict__ gcnt,
               int* __restrict__ buckets, int E) {
    __shared__ int lcnt[NB], gbase[NB];
    const int t = threadIdx.x;
    for (int i = t; i < NB; i += 256) lcnt[i] = 0;
    __syncthreads();
    const int e0 = blockIdx.x * EPB_A + t;
    int packed[16], lpos[16], bb[16];
#pragma unroll
    for (int j = 0; j < 16; ++j) {
        int e = e0 + j * 256;
        if (e < E) {
            int s = ei[e], d = ei[E + e];
            int b = d >> 6;
            bb[j] = b;
            packed[j] = ((d & 63) << 16) | s;
            lpos[j] = atomicAdd(&lcnt[b], 1);
        } else bb[j] = -1;
    }
    __syncthreads();
    for (int i = t; i < NB; i += 256)
        gbase[i] = atomicAdd(&gcnt[i], lcnt[i]);
    __syncthreads();
#pragma unroll
    for (int j = 0; j < 16; ++j)
        if (bb[j] >= 0)
            buckets[bb[j] * BCAP + gbase[bb[j]] + lpos[j]] = packed[j];
}

// ---------------------------------------------------------------------------
// Mega kernel: one block per bucket (64 nodes), 512 threads = 8 waves.
// LDS-only counting sort -> in-LDS gather-sum (agg) -> 3-layer MFMA MLP
// -> sigmoid head. No sorted_src/offsets/agg global round trips.
//   bufA[64][264]: [agg_bf(0..127) | x_bf(128..255)], later overlaid by h1.
//   bufH0[64][136]: h0.
// MFMA frag layouts (R4-R6 validated): A/B [row=lane&15][k=quad*8+j],
// C/D col=lane&15, row=quad*4+reg. Waves tiled wm(2) x wn(4).
// LDS total ~102 KB -> 1 block/CU (157 blocks on 256 CUs).
// ---------------------------------------------------------------------------
__global__ __launch_bounds__(512)
void mega_kernel(const int* __restrict__ gcnt, const int* __restrict__ buckets,
                 const u16* __restrict__ x_bf,
                 const u16* __restrict__ Wcat, const u16* __restrict__ W1b,
                 const u16* __restrict__ W2b,
                 const float* __restrict__ b_rel, const float* __restrict__ b1,
                 const float* __restrict__ b2, const float* __restrict__ W3,
                 const float* __restrict__ b3, float* __restrict__ out, int M) {
    __shared__ int edges[BCAP];        // 32 KB
    __shared__ u16 ssrc[BCAP];         // 16 KB
    __shared__ u16 bufA[64 * 264];     // 33.8 KB
    __shared__ u16 bufH0[64 * 136];    // 17.4 KB
    __shared__ int deg[64], cur[64], sbeg[64];
    __shared__ float part[64][4];
    const int b = blockIdx.x, t = threadIdx.x;
    const int w = t >> 6, lane = t & 63;
    const int wm = w >> 2, wn = w & 3;           // 2 x 4 wave tiling
    const int l16 = lane & 15, q = lane >> 4;
    const int r0 = b * 64;

    // --- stage bucket edges + per-node histogram ---
    if (t < 64) deg[t] = 0;
    __syncthreads();
    int cnt = gcnt[b]; if (cnt > BCAP) cnt = BCAP;
    for (int i = t; i < cnt; i += 512) {
        int p = buckets[b * BCAP + i];
        edges[i] = p;
        atomicAdd(&deg[p >> 16], 1);
    }
    __syncthreads();
    // --- local exclusive scan (wave 0) ---
    if (t < 64) {
        int d = deg[t];
        int incl = d;
#pragma unroll
        for (int off = 1; off < 64; off <<= 1) {
            int o = __shfl_up(incl, off);
            if (t >= off) incl += o;
        }
        int excl = incl - d;
        cur[t] = excl;
        sbeg[t] = excl;
    }
    __syncthreads();
    // --- in-LDS counting-sort scatter + stage root half of bufA ---
    for (int i = t; i < cnt; i += 512) {
        int p = edges[i];
        int pos = atomicAdd(&cur[p >> 16], 1);
        ssrc[pos] = (u16)(p & 0xffff);
    }
    for (int idx = t; idx < 64 * 16; idx += 512) {   // 64 rows x 16 chunks of 8
        int row = idx >> 4, kc = (idx & 15) * 8;
        int gr = r0 + row; if (gr >= M) gr = M - 1;
        bf16x8 v = *reinterpret_cast<const bf16x8*>(x_bf + (size_t)gr * D_IN + kc);
        *reinterpret_cast<bf16x8*>(&bufA[row * 264 + 128 + kc]) = v;
    }
    __syncthreads();
    // --- gather-sum: wave wv handles nodes wv*8..wv*8+7 ---
    {
        const int c = (lane & 31) * 4;
        const int r = lane >> 5;
        for (int j = 0; j < 8; ++j) {
            int ln = w * 8 + j;
            int beg = sbeg[ln], dg = deg[ln];
            int half = (dg + 1) >> 1;
            int i = beg + (r ? half : 0);
            const int i1 = r ? beg + dg : beg + half;
            float4 a0 = {0, 0, 0, 0}, a1 = {0, 0, 0, 0};
            float4 a2 = {0, 0, 0, 0}, a3 = {0, 0, 0, 0};
            for (; i + 4 <= i1; i += 4) {
                int s0 = ssrc[i + 0], s1 = ssrc[i + 1];
                int s2 = ssrc[i + 2], s3 = ssrc[i + 3];
                ushort4 v0 = *reinterpret_cast<const ushort4*>(x_bf + (size_t)s0 * D_IN + c);
                ushort4 v1 = *reinterpret_cast<const ushort4*>(x_bf + (size_t)s1 * D_IN + c);
                ushort4 v2 = *reinterpret_cast<const ushort4*>(x_bf + (size_t)s2 * D_IN + c);
                ushort4 v3 = *reinterpret_cast<const ushort4*>(x_bf + (size_t)s3 * D_IN + c);
                a0.x += bf2f(v0.x); a0.y += bf2f(v0.y); a0.z += bf2f(v0.z); a0.w += bf2f(v0.w);
                a1.x += bf2f(v1.x); a1.y += bf2f(v1.y); a1.z += bf2f(v1.z); a1.w += bf2f(v1.w);
                a2.x += bf2f(v2.x); a2.y += bf2f(v2.y); a2.z += bf2f(v2.z); a2.w += bf2f(v2.w);
                a3.x += bf2f(v3.x); a3.y += bf2f(v3.y); a3.z += bf2f(v3.z); a3.w += bf2f(v3.w);
            }
            for (; i < i1; ++i) {
                int s = ssrc[i];
                ushort4 v = *reinterpret_cast<const ushort4*>(x_bf + (size_t)s * D_IN + c);
                a0.x += bf2f(v.x); a0.y += bf2f(v.y); a0.z += bf2f(v.z); a0.w += bf2f(v.w);
            }
            a0.x += a1.x + a2.x + a3.x;
            a0.y += a1.y + a2.y + a3.y;
            a0.z += a1.z + a2.z + a3.z;
            a0.w += a1.w + a2.w + a3.w;
            a0.x += __shfl_xor(a0.x, 32);
            a0.y += __shfl_xor(a0.y, 32);
            a0.z += __shfl_xor(a0.z, 32);
            a0.w += __shfl_xor(a0.w, 32);
            if (r == 0) {
                ushort4 o;
                o.x = f2bf(a0.x); o.y = f2bf(a0.y); o.z = f2bf(a0.z); o.w = f2bf(a0.w);
                *reinterpret_cast<ushort4*>(&bufA[ln * 264 + c]) = o;
            }
        }
    }
    __syncthreads();

    // --- Phase 1: h0[64][128] = A_in @ Wcat^T + b_rel ---
    {
        f32x4 acc[2][2] = {};
#pragma unroll
        for (int k0 = 0; k0 < 256; k0 += 32) {
            bf16x8 af[2];
#pragma unroll
            for (int i = 0; i < 2; ++i)
                af[i] = *reinterpret_cast<const bf16x8*>(
                    &bufA[(wm * 32 + i * 16 + l16) * 264 + k0 + q * 8]);
#pragma unroll
            for (int jj = 0; jj < 2; ++jj) {
                int col = wn * 32 + jj * 16 + l16;
                bf16x8 bv = *reinterpret_cast<const bf16x8*>(
                    Wcat + (size_t)col * 256 + k0 + q * 8);
                acc[0][jj] = __builtin_amdgcn_mfma_f32_16x16x32_bf16(af[0], bv, acc[0][jj], 0, 0, 0);
                acc[1][jj] = __builtin_amdgcn_mfma_f32_16x16x32_bf16(af[1], bv, acc[1][jj], 0, 0, 0);
            }
        }
#pragma unroll
        for (int i = 0; i < 2; ++i)
#pragma unroll
            for (int jj = 0; jj < 2; ++jj) {
                int col = wn * 32 + jj * 16 + l16;
                float bb = b_rel[col];
#pragma unroll
                for (int r = 0; r < 4; ++r) {
                    int row = wm * 32 + i * 16 + q * 4 + r;
                    bufH0[row * 136 + col] = f2bf(acc[i][jj][r] + bb);
                }
            }
    }
    __syncthreads();

    // --- Phase 2: h1[64][256] = relu(h0 @ W1^T + b1); h1 overlays bufA ---
    {
        f32x4 acc[2][4] = {};
#pragma unroll
        for (int k0 = 0; k0 < 128; k0 += 32) {
            bf16x8 af[2];
#pragma unroll
            for (int i = 0; i < 2; ++i)
                af[i] = *reinterpret_cast<const bf16x8*>(
                    &bufH0[(wm * 32 + i * 16 + l16) * 136 + k0 + q * 8]);
#pragma unroll
            for (int jj = 0; jj < 4; ++jj) {
                int col = wn * 64 + jj * 16 + l16;
                bf16x8 bv = *reinterpret_cast<const bf16x8*>(
                    W1b + (size_t)col * 128 + k0 + q * 8);
                acc[0][jj] = __builtin_amdgcn_mfma_f32_16x16x32_bf16(af[0], bv, acc[0][jj], 0, 0, 0);
                acc[1][jj] = __builtin_amdgcn_mfma_f32_16x16x32_bf16(af[1], bv, acc[1][jj], 0, 0, 0);
            }
        }
        __syncthreads();  // all phase-1 bufA reads complete before overlay
#pragma unroll
        for (int i = 0; i < 2; ++i)
#pragma unroll
            for (int jj = 0; jj < 4; ++jj) {
                int col = wn * 64 + jj * 16 + l16;
                float bb = b1[col];
#pragma unroll
                for (int r = 0; r < 4; ++r) {
                    int row = wm * 32 + i * 16 + q * 4 + r;
                    bufA[row * 264 + col] = f2bf(fmaxf(acc[i][jj][r] + bb, 0.f));
                }
            }
    }
    __syncthreads();

    // --- Phase 3 + head: h2 = relu(h1 @ W2^T + b2); out = sigmoid(h2@W3+b3) ---
    {
        f32x4 acc[2][4] = {};
#pragma unroll
        for (int k0 = 0; k0 < 256; k0 += 32) {
            bf16x8 af[2];
#pragma unroll
            for (int i = 0; i < 2; ++i)
                af[i] = *reinterpret_cast<const bf16x8*>(
                    &bufA[(wm * 32 + i * 16 + l16) * 264 + k0 + q * 8]);
#pragma unroll
            for (int jj = 0; jj < 4; ++jj) {
                int col = wn * 64 + jj * 16 + l16;
                bf16x8 bv = *reinterpret_cast<const bf16x8*>(
                    W2b + (size_t)col * 256 + k0 + q * 8);
                acc[0][jj] = __builtin_amdgcn_mfma_f32_16x16x32_bf16(af[0], bv, acc[0][jj], 0, 0, 0);
                acc[1][jj] = __builtin_amdgcn_mfma_f32_16x16x32_bf16(af[1], bv, acc[1][jj], 0, 0, 0);
            }
        }
        float s[2][4] = {};
#pragma unroll
        for (int jj = 0; jj < 4; ++jj) {
            int col = wn * 64 + jj * 16 + l16;
            float bb = b2[col], ww = W3[col];
#pragma unroll
            for (int i = 0; i < 2; ++i)
#pragma unroll
                for (int r = 0; r < 4; ++r)
                    s[i][r] = fmaf(fmaxf(acc[i][jj][r] + bb, 0.f), ww, s[i][r]);
        }
#pragma unroll
        for (int off = 1; off < 16; off <<= 1)
#pragma unroll
            for (int i = 0; i < 2; ++i)
#pragma unroll
                for (int r = 0; r < 4; ++r)
                    s[i][r] += __shfl_xor(s[i][r], off);
        if (l16 == 0)
#pragma unroll
            for (int i = 0; i < 2; ++i)
#pragma unroll
                for (int r = 0; r < 4; ++r)
                    part[wm * 32 + i * 16 + q * 4 + r][wn] = s[i][r];
    }
    __syncthreads();
    if (t < 64) {
        int node = r0 + t;
        if (node < M) {
            float v = part[t][0] + part[t][1] + part[t][2] + part[t][3] + b3[0];
            out[node] = 1.0f / (1.0f + expf(-v));
        }
    }
}

extern "C" void kernel_launch(void* const* d_in, const int* in_sizes, int n_in,
                              void* d_out, int out_size, void* d_ws, size_t ws_size,
                              hipStream_t stream) {
    const float* x      = (const float*)d_in[0];
    const int*   ei     = (const int*)d_in[1];   // [2, E]: src row then dst row
    const float* W_rel  = (const float*)d_in[2];
    const float* b_rel  = (const float*)d_in[3];
    const float* W_root = (const float*)d_in[4];
    const float* W1     = (const float*)d_in[5];
    const float* b1     = (const float*)d_in[6];
    const float* W2     = (const float*)d_in[7];
    const float* b2     = (const float*)d_in[8];
    const float* W3     = (const float*)d_in[9];
    const float* b3     = (const float*)d_in[10];
    float* out = (float*)d_out;
    const int E = in_sizes[1] / 2;

    char* p = (char*)d_ws;
    auto carve = [&](size_t bytes) { char* r = p; p += (bytes + 63) & ~size_t(63); return r; };
    u16* x_bf = (u16*)carve((size_t)N_NODES * D_IN * 2); // dense bf16 x
    u16* Wcat = (u16*)carve(128 * 256 * 2);
    u16* W1b  = (u16*)carve(256 * 128 * 2);
    u16* W2b  = (u16*)carve(256 * 256 * 2);
    int* gcnt    = (int*)carve(NB * 4);
    int* buckets = (int*)carve((size_t)NB * BCAP * 4);   // 5.1 MB

    prep_kernel<<<PREP_XB + PREP_WB + 1, 256, 0, stream>>>(
        x, W_rel, W_root, W1, W2, x_bf, Wcat, W1b, W2b, gcnt);
    binsort_a<<<(E + EPB_A - 1) / EPB_A, 256, 0, stream>>>(ei, gcnt, buckets, E);
    mega_kernel<<<NB, 512, 0, stream>>>(gcnt, buckets, x_bf, Wcat, W1b, W2b,
                                        b_rel, b1, b2, W3, b3, out, N_NODES);
}

// Round 8
// 132.532 us; speedup vs baseline: 9.1312x; 1.0601x over previous
//
#include <hip/hip_runtime.h>
#include <hip/hip_bf16.h>
#include <cmath>

constexpr int N_NODES = 10000;
constexpr int D_IN = 128;   // GraphConv dim
constexpr int H_DIM = 256;  // MLP hidden

// Bucket geometry: bucket = dst>>6 (64 nodes/bucket), 157 buckets.
constexpr int NB = 157;
constexpr int BCAP = 8192;      // avg 4076 edges/bucket; 6-sigma max ~4500
constexpr int EPB_A = 4096;     // edges per phase-A block (256 thr x 16)

typedef unsigned short u16;
typedef short bf16x8 __attribute__((ext_vector_type(8)));  // 8 bf16 = 4 VGPRs
typedef float f32x4 __attribute__((ext_vector_type(4)));

__device__ inline u16 f2bf(float f) {
    return __builtin_bit_cast(u16, __float2bfloat16(f));  // RNE hw cvt
}
__device__ inline float bf2f(u16 u) {
    unsigned int v = (unsigned int)u << 16;
    return __builtin_bit_cast(float, v);
}

// ---------------------------------------------------------------------------
// Prep (one kernel, 3 jobs by blockIdx):
//  blocks [0,1250):    cast x fp32 -> dense x_bf [10000,128] AND A0 rows'
//                      second half (stride 256, offset 128)
//  blocks [1250,1378): cast weights -> Wcat[128][256]=[W_rel|W_root],
//                      W1b[256][128], W2b[256][256]
//  block 1378:         zero gcnt[157]
// ---------------------------------------------------------------------------
constexpr int PREP_XB = 1250, PREP_WB = 128;
__global__ __launch_bounds__(256)
void prep_kernel(const float* __restrict__ x,
                 const float* __restrict__ W_rel, const float* __restrict__ W_root,
                 const float* __restrict__ W1, const float* __restrict__ W2,
                 u16* __restrict__ x_bf, u16* __restrict__ A0,
                 u16* __restrict__ Wcat, u16* __restrict__ W1b, u16* __restrict__ W2b,
                 int* __restrict__ gcnt) {
    const int bid = blockIdx.x, t = threadIdx.x;
    if (bid < PREP_XB) {
        int idx = bid * 256 + t;                 // float4 chunk id
        if (idx >= N_NODES * 32) return;
        int row = idx >> 5, c = (idx & 31) * 4;
        float4 v = *reinterpret_cast<const float4*>(x + (size_t)row * D_IN + c);
        ushort4 o;
        o.x = f2bf(v.x); o.y = f2bf(v.y); o.z = f2bf(v.z); o.w = f2bf(v.w);
        *reinterpret_cast<ushort4*>(x_bf + (size_t)row * D_IN + c) = o;
        *reinterpret_cast<ushort4*>(A0 + (size_t)row * 256 + 128 + c) = o;
    } else if (bid < PREP_XB + PREP_WB) {
        int idx4 = ((bid - PREP_XB) * 256 + t) * 4;   // 131072 weight elems
        const float* src;
        u16* dst;
        if (idx4 < 32768) {            // Wcat
            int n = idx4 >> 8, k = idx4 & 255;
            src = (k < 128) ? W_rel + n * 128 + k : W_root + n * 128 + (k - 128);
            dst = Wcat + idx4;
        } else if (idx4 < 65536) {     // W1
            src = W1 + (idx4 - 32768);
            dst = W1b + (idx4 - 32768);
        } else {                       // W2
            src = W2 + (idx4 - 65536);
            dst = W2b + (idx4 - 65536);
        }
        float4 v = *reinterpret_cast<const float4*>(src);
        ushort4 o;
        o.x = f2bf(v.x); o.y = f2bf(v.y); o.z = f2bf(v.z); o.w = f2bf(v.w);
        *reinterpret_cast<ushort4*>(dst) = o;
    } else {
        if (t < NB) gcnt[t] = 0;
    }
}

// ---------------------------------------------------------------------------
// Phase A: bucket edges by dst>>6. LDS hist + one cursor reservation per
// (block,bucket) -> ~100B contiguous write runs (mostly full lines).
// packed = (dst & 63) << 16 | src   (src < 65536).
// ---------------------------------------------------------------------------
__global__ __launch_bounds__(256)
void binsort_a(const int* __restrict__ ei, int* __restrict__ gcnt,
               int* __restrict__ buckets, int E) {
    __shared__ int lcnt[NB], gbase[NB];
    const int t = threadIdx.x;
    for (int i = t; i < NB; i += 256) lcnt[i] = 0;
    __syncthreads();
    const int e0 = blockIdx.x * EPB_A + t;
    int packed[16], lpos[16], bb[16];
#pragma unroll
    for (int j = 0; j < 16; ++j) {
        int e = e0 + j * 256;
        if (e < E) {
            int s = ei[e], d = ei[E + e];
            int b = d >> 6;
            bb[j] = b;
            packed[j] = ((d & 63) << 16) | s;
            lpos[j] = atomicAdd(&lcnt[b], 1);
        } else bb[j] = -1;
    }
    __syncthreads();
    for (int i = t; i < NB; i += 256)
        gbase[i] = atomicAdd(&gcnt[i], lcnt[i]);
    __syncthreads();
#pragma unroll
    for (int j = 0; j < 16; ++j)
        if (bb[j] >= 0)
            buckets[bb[j] * BCAP + gbase[bb[j]] + lpos[j]] = packed[j];
}

// ---------------------------------------------------------------------------
// Phase B: one block per bucket. Inline redundant 157-scan of gcnt gives this
// bucket's base. Stage edges in LDS, 64-way per-node hist + wave scan ->
// contiguous single-CU writes of sorted_src; emits offsets[] (telescopes).
// ---------------------------------------------------------------------------
__global__ __launch_bounds__(256)
void binsort_b(const int* __restrict__ gcnt, const int* __restrict__ buckets,
               int* __restrict__ sorted_src, int* __restrict__ offsets, int E) {
    __shared__ int edges[BCAP];
    __shared__ int deg[64], cur[64];
    __shared__ int sbase;
    const int b = blockIdx.x, t = threadIdx.x;
    if (t < 64) {  // wave 0: exclusive scan of gcnt[0..NB) to find base[b]
        int v[3], sum = 0;
#pragma unroll
        for (int j = 0; j < 3; ++j) {
            int idx = t * 3 + j;
            int d = (idx < NB) ? gcnt[idx] : 0;
            v[j] = sum;
            sum += d;
        }
        int incl = sum;
#pragma unroll
        for (int off = 1; off < 64; off <<= 1) {
            int o = __shfl_up(incl, off);
            if (t >= off) incl += o;
        }
        int excl = incl - sum;
#pragma unroll
        for (int j = 0; j < 3; ++j)
            if (t * 3 + j == b) sbase = excl + v[j];
    }
    if (t < 64) deg[t] = 0;
    if (b == 0 && t == 0) offsets[N_NODES] = E;
    __syncthreads();
    const int base = sbase;
    int cnt = gcnt[b]; if (cnt > BCAP) cnt = BCAP;
    for (int i = t; i < cnt; i += 256) {
        int p = buckets[b * BCAP + i];
        edges[i] = p;
        atomicAdd(&deg[p >> 16], 1);
    }
    __syncthreads();
    if (t < 64) {
        int d = deg[t];
        int incl = d;
#pragma unroll
        for (int off = 1; off < 64; off <<= 1) {
            int o = __shfl_up(incl, off);
            if (t >= off) incl += o;
        }
        int excl = incl - d;
        cur[t] = excl;
        int node = b * 64 + t;
        if (node < N_NODES) offsets[node] = base + excl;
    }
    __syncthreads();
    for (int i = t; i < cnt; i += 256) {
        int p = edges[i];
        int pos = atomicAdd(&cur[p >> 16], 1);
        sorted_src[base + pos] = p & 0xffff;
    }
}

// ---------------------------------------------------------------------------
// Gather-sum over bf16 x (2.56 MB, L2-resident). One wave per node (10000
// waves -> latency fully hidden; the R7 mega form had only 1256 waves and
// collapsed to 8x serialization). ILP x4, fp32 acc, bf16 out into A0 half.
// ---------------------------------------------------------------------------
__global__ __launch_bounds__(256)
void gather_sum_kernel(const u16* __restrict__ x_bf,
                       const int* __restrict__ offsets,
                       const int* __restrict__ sorted_src,
                       u16* __restrict__ A0, int M) {
    int wid = (blockIdx.x * blockDim.x + threadIdx.x) >> 6;
    if (wid >= M) return;
    int lane = threadIdx.x & 63;
    int c = (lane & 31) * 4;
    int r = lane >> 5;
    int beg = offsets[wid], end = offsets[wid + 1];
    int half = (end - beg + 1) >> 1;
    int i = r ? beg + half : beg;
    const int i1 = r ? end : beg + half;
    float4 a0 = {0, 0, 0, 0}, a1 = {0, 0, 0, 0}, a2 = {0, 0, 0, 0}, a3 = {0, 0, 0, 0};
    for (; i + 4 <= i1; i += 4) {
        int s0 = sorted_src[i + 0], s1 = sorted_src[i + 1];
        int s2 = sorted_src[i + 2], s3 = sorted_src[i + 3];
        ushort4 v0 = *reinterpret_cast<const ushort4*>(x_bf + (size_t)s0 * D_IN + c);
        ushort4 v1 = *reinterpret_cast<const ushort4*>(x_bf + (size_t)s1 * D_IN + c);
        ushort4 v2 = *reinterpret_cast<const ushort4*>(x_bf + (size_t)s2 * D_IN + c);
        ushort4 v3 = *reinterpret_cast<const ushort4*>(x_bf + (size_t)s3 * D_IN + c);
        a0.x += bf2f(v0.x); a0.y += bf2f(v0.y); a0.z += bf2f(v0.z); a0.w += bf2f(v0.w);
        a1.x += bf2f(v1.x); a1.y += bf2f(v1.y); a1.z += bf2f(v1.z); a1.w += bf2f(v1.w);
        a2.x += bf2f(v2.x); a2.y += bf2f(v2.y); a2.z += bf2f(v2.z); a2.w += bf2f(v2.w);
        a3.x += bf2f(v3.x); a3.y += bf2f(v3.y); a3.z += bf2f(v3.z); a3.w += bf2f(v3.w);
    }
    for (; i < i1; ++i) {
        int s = sorted_src[i];
        ushort4 v = *reinterpret_cast<const ushort4*>(x_bf + (size_t)s * D_IN + c);
        a0.x += bf2f(v.x); a0.y += bf2f(v.y); a0.z += bf2f(v.z); a0.w += bf2f(v.w);
    }
    a0.x += a1.x + a2.x + a3.x;
    a0.y += a1.y + a2.y + a3.y;
    a0.z += a1.z + a2.z + a3.z;
    a0.w += a1.w + a2.w + a3.w;
    a0.x += __shfl_xor(a0.x, 32);
    a0.y += __shfl_xor(a0.y, 32);
    a0.z += __shfl_xor(a0.z, 32);
    a0.w += __shfl_xor(a0.w, 32);
    if (r == 0) {
        ushort4 o;
        o.x = f2bf(a0.x); o.y = f2bf(a0.y); o.z = f2bf(a0.z); o.w = f2bf(a0.w);
        *reinterpret_cast<ushort4*>(A0 + (size_t)wid * 256 + c) = o;
    }
}

// ---------------------------------------------------------------------------
// Fused MLP, weight-LDS edition. One block per 64 rows, 512 thr = 8 waves
// tiled wm(2) x wn(4). Each phase STAGES its weight matrix into LDS first
// (coalesced), fixing R6/R7's per-MFMA global B-fragment latency stall
// (MfmaUtil 1.8%). W2 (128 KB) is staged in two 128-col halves.
//   bufA[64][264]: [agg|x] input, overlaid by h1 after phase 2.
//   bufH0[64][136]: h0.   wbuf: current weight tile (<=69.6 KB).
// LDS total ~122 KB -> 1 block/CU; MFMA per block ~1024 instrs.
// Frag layouts (R4-R7 validated): A/B [row=lane&15][k=quad*8+j],
// C/D col=lane&15, row=quad*4+reg. Strides 264/136 u16 (2-way, free).
// ---------------------------------------------------------------------------
__global__ __launch_bounds__(512)
void fused_mlp(const u16* __restrict__ A0, const u16* __restrict__ Wcat,
               const u16* __restrict__ W1b, const u16* __restrict__ W2b,
               const float* __restrict__ b_rel, const float* __restrict__ b1,
               const float* __restrict__ b2, const float* __restrict__ W3,
               const float* __restrict__ b3, float* __restrict__ out, int M) {
    __shared__ u16 bufA[64 * 264];     // 33.8 KB
    __shared__ u16 bufH0[64 * 136];    // 17.4 KB
    __shared__ u16 wbuf[34816];        // 69.6 KB (max: W1b 256x136)
    __shared__ float part[64][4];
    const int t = threadIdx.x, b = blockIdx.x;
    const int w = t >> 6, lane = t & 63;
    const int wm = w >> 2, wn = w & 3;
    const int l16 = lane & 15, q = lane >> 4;
    const int r0 = b * 64;

    // Stage A rows [64][256] + Wcat [128][256] into LDS.
    for (int idx = t; idx < 64 * 32; idx += 512) {
        int row = idx >> 5, kc = (idx & 31) * 8;
        int gr = r0 + row; if (gr >= M) gr = M - 1;
        bf16x8 v = *reinterpret_cast<const bf16x8*>(A0 + (size_t)gr * 256 + kc);
        *reinterpret_cast<bf16x8*>(&bufA[row * 264 + kc]) = v;
    }
    for (int idx = t; idx < 128 * 32; idx += 512) {
        int row = idx >> 5, kc = (idx & 31) * 8;
        bf16x8 v = *reinterpret_cast<const bf16x8*>(Wcat + (size_t)row * 256 + kc);
        *reinterpret_cast<bf16x8*>(&wbuf[row * 264 + kc]) = v;
    }
    __syncthreads();

    // Phase 1: h0[64][128] = A @ Wcat^T + b_rel  (jj = 128/4/16 = 2)
    {
        f32x4 acc[2][2] = {};
#pragma unroll
        for (int k0 = 0; k0 < 256; k0 += 32) {
            bf16x8 af[2];
#pragma unroll
            for (int i = 0; i < 2; ++i)
                af[i] = *reinterpret_cast<const bf16x8*>(
                    &bufA[(wm * 32 + i * 16 + l16) * 264 + k0 + q * 8]);
#pragma unroll
            for (int jj = 0; jj < 2; ++jj) {
                int col = wn * 32 + jj * 16 + l16;
                bf16x8 bv = *reinterpret_cast<const bf16x8*>(
                    &wbuf[col * 264 + k0 + q * 8]);
                acc[0][jj] = __builtin_amdgcn_mfma_f32_16x16x32_bf16(af[0], bv, acc[0][jj], 0, 0, 0);
                acc[1][jj] = __builtin_amdgcn_mfma_f32_16x16x32_bf16(af[1], bv, acc[1][jj], 0, 0, 0);
            }
        }
#pragma unroll
        for (int i = 0; i < 2; ++i)
#pragma unroll
            for (int jj = 0; jj < 2; ++jj) {
                int col = wn * 32 + jj * 16 + l16;
                float bb = b_rel[col];
#pragma unroll
                for (int r = 0; r < 4; ++r) {
                    int row = wm * 32 + i * 16 + q * 4 + r;
                    bufH0[row * 136 + col] = f2bf(acc[i][jj][r] + bb);
                }
            }
    }
    __syncthreads();   // wbuf reads + bufH0 writes complete

    // Stage W1b [256][128] (stride 136).
    for (int idx = t; idx < 256 * 16; idx += 512) {
        int row = idx >> 4, kc = (idx & 15) * 8;
        bf16x8 v = *reinterpret_cast<const bf16x8*>(W1b + (size_t)row * 128 + kc);
        *reinterpret_cast<bf16x8*>(&wbuf[row * 136 + kc]) = v;
    }
    __syncthreads();

    // Phase 2: h1[64][256] = relu(h0 @ W1^T + b1); h1 overlays bufA (jj=4)
    {
        f32x4 acc[2][4] = {};
#pragma unroll
        for (int k0 = 0; k0 < 128; k0 += 32) {
            bf16x8 af[2];
#pragma unroll
            for (int i = 0; i < 2; ++i)
                af[i] = *reinterpret_cast<const bf16x8*>(
                    &bufH0[(wm * 32 + i * 16 + l16) * 136 + k0 + q * 8]);
#pragma unroll
            for (int jj = 0; jj < 4; ++jj) {
                int col = wn * 64 + jj * 16 + l16;
                bf16x8 bv = *reinterpret_cast<const bf16x8*>(
                    &wbuf[col * 136 + k0 + q * 8]);
                acc[0][jj] = __builtin_amdgcn_mfma_f32_16x16x32_bf16(af[0], bv, acc[0][jj], 0, 0, 0);
                acc[1][jj] = __builtin_amdgcn_mfma_f32_16x16x32_bf16(af[1], bv, acc[1][jj], 0, 0, 0);
            }
        }
#pragma unroll
        for (int i = 0; i < 2; ++i)
#pragma unroll
            for (int jj = 0; jj < 4; ++jj) {
                int col = wn * 64 + jj * 16 + l16;
                float bb = b1[col];
#pragma unroll
                for (int r = 0; r < 4; ++r) {
                    int row = wm * 32 + i * 16 + q * 4 + r;
                    bufA[row * 264 + col] = f2bf(fmaxf(acc[i][jj][r] + bb, 0.f));
                }
            }
    }

    // Phase 3 + head, in two 128-col halves of W2 (wbuf too small for 256).
    float s[2][4] = {};
#pragma unroll
    for (int h = 0; h < 2; ++h) {
        __syncthreads();   // previous wbuf readers done (and h1 writes done)
        for (int idx = t; idx < 128 * 32; idx += 512) {
            int row = idx >> 5, kc = (idx & 31) * 8;
            bf16x8 v = *reinterpret_cast<const bf16x8*>(
                W2b + (size_t)(h * 128 + row) * 256 + kc);
            *reinterpret_cast<bf16x8*>(&wbuf[row * 264 + kc]) = v;
        }
        __syncthreads();
        f32x4 acc[2][2] = {};
#pragma unroll
        for (int k0 = 0; k0 < 256; k0 += 32) {
            bf16x8 af[2];
#pragma unroll
            for (int i = 0; i < 2; ++i)
                af[i] = *reinterpret_cast<const bf16x8*>(
                    &bufA[(wm * 32 + i * 16 + l16) * 264 + k0 + q * 8]);
#pragma unroll
            for (int jj = 0; jj < 2; ++jj) {
                int lcol = wn * 32 + jj * 16 + l16;
                bf16x8 bv = *reinterpret_cast<const bf16x8*>(
                    &wbuf[lcol * 264 + k0 + q * 8]);
                acc[0][jj] = __builtin_amdgcn_mfma_f32_16x16x32_bf16(af[0], bv, acc[0][jj], 0, 0, 0);
                acc[1][jj] = __builtin_amdgcn_mfma_f32_16x16x32_bf16(af[1], bv, acc[1][jj], 0, 0, 0);
            }
        }
#pragma unroll
        for (int jj = 0; jj < 2; ++jj) {
            int col = h * 128 + wn * 32 + jj * 16 + l16;
            float bb = b2[col], ww = W3[col];
#pragma unroll
            for (int i = 0; i < 2; ++i)
#pragma unroll
                for (int r = 0; r < 4; ++r)
                    s[i][r] = fmaf(fmaxf(acc[i][jj][r] + bb, 0.f), ww, s[i][r]);
        }
    }
#pragma unroll
    for (int off = 1; off < 16; off <<= 1)
#pragma unroll
        for (int i = 0; i < 2; ++i)
#pragma unroll
            for (int r = 0; r < 4; ++r)
                s[i][r] += __shfl_xor(s[i][r], off);
    if (l16 == 0)
#pragma unroll
        for (int i = 0; i < 2; ++i)
#pragma unroll
            for (int r = 0; r < 4; ++r)
                part[wm * 32 + i * 16 + q * 4 + r][wn] = s[i][r];
    __syncthreads();
    if (t < 64) {
        int node = r0 + t;
        if (node < M) {
            float v = part[t][0] + part[t][1] + part[t][2] + part[t][3] + b3[0];
            out[node] = 1.0f / (1.0f + expf(-v));
        }
    }
}

extern "C" void kernel_launch(void* const* d_in, const int* in_sizes, int n_in,
                              void* d_out, int out_size, void* d_ws, size_t ws_size,
                              hipStream_t stream) {
    const float* x      = (const float*)d_in[0];
    const int*   ei     = (const int*)d_in[1];   // [2, E]: src row then dst row
    const float* W_rel  = (const float*)d_in[2];
    const float* b_rel  = (const float*)d_in[3];
    const float* W_root = (const float*)d_in[4];
    const float* W1     = (const float*)d_in[5];
    const float* b1     = (const float*)d_in[6];
    const float* W2     = (const float*)d_in[7];
    const float* b2     = (const float*)d_in[8];
    const float* W3     = (const float*)d_in[9];
    const float* b3     = (const float*)d_in[10];
    float* out = (float*)d_out;
    const int E = in_sizes[1] / 2;

    char* p = (char*)d_ws;
    auto carve = [&](size_t bytes) { char* r = p; p += (bytes + 63) & ~size_t(63); return r; };
    u16* A0   = (u16*)carve((size_t)N_NODES * 256 * 2);  // [agg_bf | x_bf] rows
    u16* x_bf = (u16*)carve((size_t)N_NODES * D_IN * 2); // dense bf16 x
    u16* Wcat = (u16*)carve(128 * 256 * 2);
    u16* W1b  = (u16*)carve(256 * 128 * 2);
    u16* W2b  = (u16*)carve(256 * 256 * 2);
    int* offsets    = (int*)carve((N_NODES + 4) * 4);
    int* gcnt       = (int*)carve(NB * 4);
    int* buckets    = (int*)carve((size_t)NB * BCAP * 4);   // 5.1 MB
    int* sorted_src = (int*)carve((size_t)E * 4);

    prep_kernel<<<PREP_XB + PREP_WB + 1, 256, 0, stream>>>(
        x, W_rel, W_root, W1, W2, x_bf, A0, Wcat, W1b, W2b, gcnt);
    binsort_a<<<(E + EPB_A - 1) / EPB_A, 256, 0, stream>>>(ei, gcnt, buckets, E);
    binsort_b<<<NB, 256, 0, stream>>>(gcnt, buckets, sorted_src, offsets, E);
    gather_sum_kernel<<<(N_NODES * 64 + 255) / 256, 256, 0, stream>>>(
        x_bf, offsets, sorted_src, A0, N_NODES);
    fused_mlp<<<NB, 512, 0, stream>>>(A0, Wcat, W1b, W2b,
                                      b_rel, b1, b2, W3, b3, out, N_NODES);
}

// Round 9
// 126.927 us; speedup vs baseline: 9.5345x; 1.0442x over previous
//
#include <hip/hip_runtime.h>
#include <hip/hip_bf16.h>
#include <cmath>

constexpr int N_NODES = 10000;
constexpr int D_IN = 128;   // GraphConv dim
constexpr int H_DIM = 256;  // MLP hidden

// Bucket geometry: bucket = dst>>5 (32 nodes/bucket), 313 buckets.
constexpr int NB = 313;
constexpr int BCAP = 3072;      // avg 2045 edges/bucket, sigma ~45 -> 22-sigma margin
constexpr int EPB_A = 2048;     // edges per phase-A block (256 thr x 8)

typedef unsigned short u16;
typedef short bf16x8 __attribute__((ext_vector_type(8)));  // 8 bf16 = 4 VGPRs
typedef float f32x4 __attribute__((ext_vector_type(4)));

__device__ inline u16 f2bf(float f) {
    return __builtin_bit_cast(u16, __float2bfloat16(f));  // RNE hw cvt
}
__device__ inline float bf2f(u16 u) {
    unsigned int v = (unsigned int)u << 16;
    return __builtin_bit_cast(float, v);
}

// ---------------------------------------------------------------------------
// Prep (one kernel, 3 jobs by blockIdx):
//  blocks [0,1250):    cast x fp32 -> dense x_bf [10000,128]
//  blocks [1250,1378): cast weights -> Wcat[128][256]=[W_rel|W_root],
//                      W1b[256][128], W2b[256][256]
//  block 1378:         zero gcnt[313]
// ---------------------------------------------------------------------------
constexpr int PREP_XB = 1250, PREP_WB = 128;
__global__ __launch_bounds__(256)
void prep_kernel(const float* __restrict__ x,
                 const float* __restrict__ W_rel, const float* __restrict__ W_root,
                 const float* __restrict__ W1, const float* __restrict__ W2,
                 u16* __restrict__ x_bf,
                 u16* __restrict__ Wcat, u16* __restrict__ W1b, u16* __restrict__ W2b,
                 int* __restrict__ gcnt) {
    const int bid = blockIdx.x, t = threadIdx.x;
    if (bid < PREP_XB) {
        int idx = bid * 256 + t;                 // float4 chunk id
        if (idx >= N_NODES * 32) return;
        int row = idx >> 5, c = (idx & 31) * 4;
        float4 v = *reinterpret_cast<const float4*>(x + (size_t)row * D_IN + c);
        ushort4 o;
        o.x = f2bf(v.x); o.y = f2bf(v.y); o.z = f2bf(v.z); o.w = f2bf(v.w);
        *reinterpret_cast<ushort4*>(x_bf + (size_t)row * D_IN + c) = o;
    } else if (bid < PREP_XB + PREP_WB) {
        int idx4 = ((bid - PREP_XB) * 256 + t) * 4;   // 131072 weight elems
        const float* src;
        u16* dst;
        if (idx4 < 32768) {            // Wcat
            int n = idx4 >> 8, k = idx4 & 255;
            src = (k < 128) ? W_rel + n * 128 + k : W_root + n * 128 + (k - 128);
            dst = Wcat + idx4;
        } else if (idx4 < 65536) {     // W1
            src = W1 + (idx4 - 32768);
            dst = W1b + (idx4 - 32768);
        } else {                       // W2
            src = W2 + (idx4 - 65536);
            dst = W2b + (idx4 - 65536);
        }
        float4 v = *reinterpret_cast<const float4*>(src);
        ushort4 o;
        o.x = f2bf(v.x); o.y = f2bf(v.y); o.z = f2bf(v.z); o.w = f2bf(v.w);
        *reinterpret_cast<ushort4*>(dst) = o;
    } else {
        for (int i = t; i < NB; i += 256) gcnt[i] = 0;
    }
}

// ---------------------------------------------------------------------------
// Phase A: bucket edges by dst>>5. LDS hist + one cursor reservation per
// (block,bucket) -> contiguous write runs. 313 blocks (EPB 2048) so the
// whole GPU participates (R8's 157 blocks left half the CUs idle).
// packed = (dst & 31) << 16 | src   (src < 65536).
// ---------------------------------------------------------------------------
__global__ __launch_bounds__(256)
void binsort_a(const int* __restrict__ ei, int* __restrict__ gcnt,
               int* __restrict__ buckets, int E) {
    __shared__ int lcnt[NB], gbase[NB];
    const int t = threadIdx.x;
    for (int i = t; i < NB; i += 256) lcnt[i] = 0;
    __syncthreads();
    const int e0 = blockIdx.x * EPB_A + t;
    int packed[8], lpos[8], bb[8];
#pragma unroll
    for (int j = 0; j < 8; ++j) {
        int e = e0 + j * 256;
        if (e < E) {
            int s = ei[e], d = ei[E + e];
            int b = d >> 5;
            bb[j] = b;
            packed[j] = ((d & 31) << 16) | s;
            lpos[j] = atomicAdd(&lcnt[b], 1);
        } else bb[j] = -1;
    }
    __syncthreads();
    for (int i = t; i < NB; i += 256)
        gbase[i] = atomicAdd(&gcnt[i], lcnt[i]);
    __syncthreads();
#pragma unroll
    for (int j = 0; j < 8; ++j)
        if (bb[j] >= 0)
            buckets[bb[j] * BCAP + gbase[bb[j]] + lpos[j]] = packed[j];
}

// ---------------------------------------------------------------------------
// Fused sort+gather: one block per bucket (32 nodes), 512 thr = 8 waves.
// Bucket's edges staged in LDS, 32-way per-node hist + scan -> sorted src
// list stays ENTIRELY in LDS (no sorted_src/offsets global round trip).
// Then gather: wave w handles nodes w*4..w*4+3; half-wave per node-half,
// ILP x4 (8 outstanding x_bf row loads/wave), fp32 acc, bf16 agg_bf out.
// LDS ~18.5 KB -> several blocks/CU; 313 blocks covers all 256 CUs.
// ---------------------------------------------------------------------------
__global__ __launch_bounds__(512)
void sortgather(const int* __restrict__ gcnt, const int* __restrict__ buckets,
                const u16* __restrict__ x_bf, u16* __restrict__ agg_bf, int M) {
    __shared__ int edges[BCAP];        // 12 KB
    __shared__ u16 ssrc[BCAP];         // 6 KB
    __shared__ int deg[32], cur[32], sbeg[32];
    const int b = blockIdx.x, t = threadIdx.x;
    const int w = t >> 6, lane = t & 63;
    if (t < 32) deg[t] = 0;
    __syncthreads();
    int cnt = gcnt[b]; if (cnt > BCAP) cnt = BCAP;
    for (int i = t; i < cnt; i += 512) {
        int p = buckets[b * BCAP + i];
        edges[i] = p;
        atomicAdd(&deg[p >> 16], 1);
    }
    __syncthreads();
    if (t < 32) {   // exclusive scan over 32 per-node counts (wave 0)
        int d = deg[t];
        int incl = d;
#pragma unroll
        for (int off = 1; off < 32; off <<= 1) {
            int o = __shfl_up(incl, off);
            if (t >= off) incl += o;
        }
        int excl = incl - d;
        cur[t] = excl;
        sbeg[t] = excl;
    }
    __syncthreads();
    for (int i = t; i < cnt; i += 512) {
        int p = edges[i];
        int pos = atomicAdd(&cur[p >> 16], 1);
        ssrc[pos] = (u16)(p & 0xffff);
    }
    __syncthreads();
    // --- gather: wave w -> nodes w*4 .. w*4+3 ---
    const int c = (lane & 31) * 4;
    const int r = lane >> 5;
#pragma unroll
    for (int j = 0; j < 4; ++j) {
        int ln = w * 4 + j;
        int beg = sbeg[ln], dg = deg[ln];
        int half = (dg + 1) >> 1;
        int i = beg + (r ? half : 0);
        const int i1 = r ? beg + dg : beg + half;
        float4 a0 = {0, 0, 0, 0}, a1 = {0, 0, 0, 0};
        float4 a2 = {0, 0, 0, 0}, a3 = {0, 0, 0, 0};
        for (; i + 4 <= i1; i += 4) {
            int s0 = ssrc[i + 0], s1 = ssrc[i + 1];
            int s2 = ssrc[i + 2], s3 = ssrc[i + 3];
            ushort4 v0 = *reinterpret_cast<const ushort4*>(x_bf + (size_t)s0 * D_IN + c);
            ushort4 v1 = *reinterpret_cast<const ushort4*>(x_bf + (size_t)s1 * D_IN + c);
            ushort4 v2 = *reinterpret_cast<const ushort4*>(x_bf + (size_t)s2 * D_IN + c);
            ushort4 v3 = *reinterpret_cast<const ushort4*>(x_bf + (size_t)s3 * D_IN + c);
            a0.x += bf2f(v0.x); a0.y += bf2f(v0.y); a0.z += bf2f(v0.z); a0.w += bf2f(v0.w);
            a1.x += bf2f(v1.x); a1.y += bf2f(v1.y); a1.z += bf2f(v1.z); a1.w += bf2f(v1.w);
            a2.x += bf2f(v2.x); a2.y += bf2f(v2.y); a2.z += bf2f(v2.z); a2.w += bf2f(v2.w);
            a3.x += bf2f(v3.x); a3.y += bf2f(v3.y); a3.z += bf2f(v3.z); a3.w += bf2f(v3.w);
        }
        for (; i < i1; ++i) {
            int s = ssrc[i];
            ushort4 v = *reinterpret_cast<const ushort4*>(x_bf + (size_t)s * D_IN + c);
            a0.x += bf2f(v.x); a0.y += bf2f(v.y); a0.z += bf2f(v.z); a0.w += bf2f(v.w);
        }
        a0.x += a1.x + a2.x + a3.x;
        a0.y += a1.y + a2.y + a3.y;
        a0.z += a1.z + a2.z + a3.z;
        a0.w += a1.w + a2.w + a3.w;
        a0.x += __shfl_xor(a0.x, 32);
        a0.y += __shfl_xor(a0.y, 32);
        a0.z += __shfl_xor(a0.z, 32);
        a0.w += __shfl_xor(a0.w, 32);
        int node = b * 32 + ln;
        if (r == 0 && node < M) {
            ushort4 o;
            o.x = f2bf(a0.x); o.y = f2bf(a0.y); o.z = f2bf(a0.z); o.w = f2bf(a0.w);
            *reinterpret_cast<ushort4*>(agg_bf + (size_t)node * D_IN + c) = o;
        }
    }
}

// ---------------------------------------------------------------------------
// Fused MLP, weight-LDS edition (R8-validated). One block per 64 rows,
// 512 thr = 8 waves tiled wm(2) x wn(4). Each phase stages its weight
// matrix into LDS first; W2 in two 128-col halves. A-tile staged from
// agg_bf (cols 0..127) + x_bf (cols 128..255).
// Frag layouts (R4-R8 validated): A/B [row=lane&15][k=quad*8+j],
// C/D col=lane&15, row=quad*4+reg. Strides 264/136 u16 (2-way, free).
// ---------------------------------------------------------------------------
__global__ __launch_bounds__(512)
void fused_mlp(const u16* __restrict__ agg_bf, const u16* __restrict__ x_bf,
               const u16* __restrict__ Wcat, const u16* __restrict__ W1b,
               const u16* __restrict__ W2b,
               const float* __restrict__ b_rel, const float* __restrict__ b1,
               const float* __restrict__ b2, const float* __restrict__ W3,
               const float* __restrict__ b3, float* __restrict__ out, int M) {
    __shared__ u16 bufA[64 * 264];     // 33.8 KB
    __shared__ u16 bufH0[64 * 136];    // 17.4 KB
    __shared__ u16 wbuf[34816];        // 69.6 KB (max: W1b 256x136)
    __shared__ float part[64][4];
    const int t = threadIdx.x, b = blockIdx.x;
    const int w = t >> 6, lane = t & 63;
    const int wm = w >> 2, wn = w & 3;
    const int l16 = lane & 15, q = lane >> 4;
    const int r0 = b * 64;

    // Stage A rows: [agg_bf | x_bf] -> bufA[64][264], + Wcat into wbuf.
    for (int idx = t; idx < 64 * 16; idx += 512) {
        int row = idx >> 4, kc = (idx & 15) * 8;
        int gr = r0 + row; if (gr >= M) gr = M - 1;
        bf16x8 v = *reinterpret_cast<const bf16x8*>(agg_bf + (size_t)gr * D_IN + kc);
        *reinterpret_cast<bf16x8*>(&bufA[row * 264 + kc]) = v;
        bf16x8 vx = *reinterpret_cast<const bf16x8*>(x_bf + (size_t)gr * D_IN + kc);
        *reinterpret_cast<bf16x8*>(&bufA[row * 264 + 128 + kc]) = vx;
    }
    for (int idx = t; idx < 128 * 32; idx += 512) {
        int row = idx >> 5, kc = (idx & 31) * 8;
        bf16x8 v = *reinterpret_cast<const bf16x8*>(Wcat + (size_t)row * 256 + kc);
        *reinterpret_cast<bf16x8*>(&wbuf[row * 264 + kc]) = v;
    }
    __syncthreads();

    // Phase 1: h0[64][128] = A @ Wcat^T + b_rel
    {
        f32x4 acc[2][2] = {};
#pragma unroll
        for (int k0 = 0; k0 < 256; k0 += 32) {
            bf16x8 af[2];
#pragma unroll
            for (int i = 0; i < 2; ++i)
                af[i] = *reinterpret_cast<const bf16x8*>(
                    &bufA[(wm * 32 + i * 16 + l16) * 264 + k0 + q * 8]);
#pragma unroll
            for (int jj = 0; jj < 2; ++jj) {
                int col = wn * 32 + jj * 16 + l16;
                bf16x8 bv = *reinterpret_cast<const bf16x8*>(
                    &wbuf[col * 264 + k0 + q * 8]);
                acc[0][jj] = __builtin_amdgcn_mfma_f32_16x16x32_bf16(af[0], bv, acc[0][jj], 0, 0, 0);
                acc[1][jj] = __builtin_amdgcn_mfma_f32_16x16x32_bf16(af[1], bv, acc[1][jj], 0, 0, 0);
            }
        }
#pragma unroll
        for (int i = 0; i < 2; ++i)
#pragma unroll
            for (int jj = 0; jj < 2; ++jj) {
                int col = wn * 32 + jj * 16 + l16;
                float bb = b_rel[col];
#pragma unroll
                for (int r = 0; r < 4; ++r) {
                    int row = wm * 32 + i * 16 + q * 4 + r;
                    bufH0[row * 136 + col] = f2bf(acc[i][jj][r] + bb);
                }
            }
    }
    __syncthreads();   // wbuf reads + bufH0 writes complete

    // Stage W1b [256][128] (stride 136).
    for (int idx = t; idx < 256 * 16; idx += 512) {
        int row = idx >> 4, kc = (idx & 15) * 8;
        bf16x8 v = *reinterpret_cast<const bf16x8*>(W1b + (size_t)row * 128 + kc);
        *reinterpret_cast<bf16x8*>(&wbuf[row * 136 + kc]) = v;
    }
    __syncthreads();

    // Phase 2: h1[64][256] = relu(h0 @ W1^T + b1); h1 overlays bufA
    {
        f32x4 acc[2][4] = {};
#pragma unroll
        for (int k0 = 0; k0 < 128; k0 += 32) {
            bf16x8 af[2];
#pragma unroll
            for (int i = 0; i < 2; ++i)
                af[i] = *reinterpret_cast<const bf16x8*>(
                    &bufH0[(wm * 32 + i * 16 + l16) * 136 + k0 + q * 8]);
#pragma unroll
            for (int jj = 0; jj < 4; ++jj) {
                int col = wn * 64 + jj * 16 + l16;
                bf16x8 bv = *reinterpret_cast<const bf16x8*>(
                    &wbuf[col * 136 + k0 + q * 8]);
                acc[0][jj] = __builtin_amdgcn_mfma_f32_16x16x32_bf16(af[0], bv, acc[0][jj], 0, 0, 0);
                acc[1][jj] = __builtin_amdgcn_mfma_f32_16x16x32_bf16(af[1], bv, acc[1][jj], 0, 0, 0);
            }
        }
#pragma unroll
        for (int i = 0; i < 2; ++i)
#pragma unroll
            for (int jj = 0; jj < 4; ++jj) {
                int col = wn * 64 + jj * 16 + l16;
                float bb = b1[col];
#pragma unroll
                for (int r = 0; r < 4; ++r) {
                    int row = wm * 32 + i * 16 + q * 4 + r;
                    bufA[row * 264 + col] = f2bf(fmaxf(acc[i][jj][r] + bb, 0.f));
                }
            }
    }

    // Phase 3 + head, in two 128-col halves of W2.
    float s[2][4] = {};
#pragma unroll
    for (int h = 0; h < 2; ++h) {
        __syncthreads();   // previous wbuf readers done (and h1 writes done)
        for (int idx = t; idx < 128 * 32; idx += 512) {
            int row = idx >> 5, kc = (idx & 31) * 8;
            bf16x8 v = *reinterpret_cast<const bf16x8*>(
                W2b + (size_t)(h * 128 + row) * 256 + kc);
            *reinterpret_cast<bf16x8*>(&wbuf[row * 264 + kc]) = v;
        }
        __syncthreads();
        f32x4 acc[2][2] = {};
#pragma unroll
        for (int k0 = 0; k0 < 256; k0 += 32) {
            bf16x8 af[2];
#pragma unroll
            for (int i = 0; i < 2; ++i)
                af[i] = *reinterpret_cast<const bf16x8*>(
                    &bufA[(wm * 32 + i * 16 + l16) * 264 + k0 + q * 8]);
#pragma unroll
            for (int jj = 0; jj < 2; ++jj) {
                int lcol = wn * 32 + jj * 16 + l16;
                bf16x8 bv = *reinterpret_cast<const bf16x8*>(
                    &wbuf[lcol * 264 + k0 + q * 8]);
                acc[0][jj] = __builtin_amdgcn_mfma_f32_16x16x32_bf16(af[0], bv, acc[0][jj], 0, 0, 0);
                acc[1][jj] = __builtin_amdgcn_mfma_f32_16x16x32_bf16(af[1], bv, acc[1][jj], 0, 0, 0);
            }
        }
#pragma unroll
        for (int jj = 0; jj < 2; ++jj) {
            int col = h * 128 + wn * 32 + jj * 16 + l16;
            float bb = b2[col], ww = W3[col];
#pragma unroll
            for (int i = 0; i < 2; ++i)
#pragma unroll
                for (int r = 0; r < 4; ++r)
                    s[i][r] = fmaf(fmaxf(acc[i][jj][r] + bb, 0.f), ww, s[i][r]);
        }
    }
#pragma unroll
    for (int off = 1; off < 16; off <<= 1)
#pragma unroll
        for (int i = 0; i < 2; ++i)
#pragma unroll
            for (int r = 0; r < 4; ++r)
                s[i][r] += __shfl_xor(s[i][r], off);
    if (l16 == 0)
#pragma unroll
        for (int i = 0; i < 2; ++i)
#pragma unroll
            for (int r = 0; r < 4; ++r)
                part[wm * 32 + i * 16 + q * 4 + r][wn] = s[i][r];
    __syncthreads();
    if (t < 64) {
        int node = r0 + t;
        if (node < M) {
            float v = part[t][0] + part[t][1] + part[t][2] + part[t][3] + b3[0];
            out[node] = 1.0f / (1.0f + expf(-v));
        }
    }
}

extern "C" void kernel_launch(void* const* d_in, const int* in_sizes, int n_in,
                              void* d_out, int out_size, void* d_ws, size_t ws_size,
                              hipStream_t stream) {
    const float* x      = (const float*)d_in[0];
    const int*   ei     = (const int*)d_in[1];   // [2, E]: src row then dst row
    const float* W_rel  = (const float*)d_in[2];
    const float* b_rel  = (const float*)d_in[3];
    const float* W_root = (const float*)d_in[4];
    const float* W1     = (const float*)d_in[5];
    const float* b1     = (const float*)d_in[6];
    const float* W2     = (const float*)d_in[7];
    const float* b2     = (const float*)d_in[8];
    const float* W3     = (const float*)d_in[9];
    const float* b3     = (const float*)d_in[10];
    float* out = (float*)d_out;
    const int E = in_sizes[1] / 2;

    char* p = (char*)d_ws;
    auto carve = [&](size_t bytes) { char* r = p; p += (bytes + 63) & ~size_t(63); return r; };
    u16* x_bf   = (u16*)carve((size_t)N_NODES * D_IN * 2);   // dense bf16 x
    u16* agg_bf = (u16*)carve((size_t)N_NODES * D_IN * 2);   // bf16 aggregation
    u16* Wcat   = (u16*)carve(128 * 256 * 2);
    u16* W1b    = (u16*)carve(256 * 128 * 2);
    u16* W2b    = (u16*)carve(256 * 256 * 2);
    int* gcnt    = (int*)carve(NB * 4);
    int* buckets = (int*)carve((size_t)NB * BCAP * 4);       // 3.85 MB

    prep_kernel<<<PREP_XB + PREP_WB + 1, 256, 0, stream>>>(
        x, W_rel, W_root, W1, W2, x_bf, Wcat, W1b, W2b, gcnt);
    binsort_a<<<(E + EPB_A - 1) / EPB_A, 256, 0, stream>>>(ei, gcnt, buckets, E);
    sortgather<<<NB, 512, 0, stream>>>(gcnt, buckets, x_bf, agg_bf, N_NODES);
    fused_mlp<<<(N_NODES + 63) / 64, 512, 0, stream>>>(
        agg_bf, x_bf, Wcat, W1b, W2b, b_rel, b1, b2, W3, b3, out, N_NODES);
}